// Round 16
// baseline (1396.595 us; speedup 1.0000x reference)
//
#include <hip/hip_runtime.h>
#include <math.h>

#define NN   262144      // nodes
#define CIN  200         // input channels
#define EE   2097152     // edges
#define NB   (2*NN)      // flat count/ptr sections: [row | col]
#define EPSV 1e-5f

typedef __bf16 bf16x8 __attribute__((ext_vector_type(8)));
typedef float  f32x4  __attribute__((ext_vector_type(4)));

__device__ __forceinline__ unsigned short f2bf(float f) {
    unsigned int u = __float_as_uint(f);
    unsigned int r = (u + 0x7fffu + ((u >> 16) & 1u)) >> 16;
    return (unsigned short)r;
}
__device__ __forceinline__ float bf2f(unsigned short u) {
    return __uint_as_float(((unsigned int)u) << 16);
}

// ---- stem weight pre-swizzle: W[200][64] fp32 -> B-frag bf16, K padded to 224 --
__global__ __launch_bounds__(256) void w_convert_stem(
    const float* __restrict__ W, unsigned short* __restrict__ wbufS)
{
    int idx = blockIdx.x * 256 + threadIdx.x;    // 0..14335
    if (idx >= 28 * 64 * 8) return;
    int e    = idx & 7;
    int lane = (idx >> 3) & 63;
    int f    = idx >> 9;          // 0..27
    int t    = f & 3;
    int kb   = f >> 2;
    int k    = kb * 32 + ((lane >> 4) & 3) * 8 + e;
    float w  = (k < CIN) ? W[k * 64 + t * 16 + (lane & 15)] : 0.f;
    wbufS[idx] = f2bf(w);
}

// ------- stem via MFMA: t = bf16(x @ W + b), fused fp32 BN stats ---------------
__global__ __launch_bounds__(256) void stem_mfma(
    const float* __restrict__ x, const unsigned short* __restrict__ wbS,
    const float* __restrict__ bias, unsigned short* __restrict__ t,
    float* __restrict__ stats)
{
    const int lane = threadIdx.x & 63;
    const int wloc = threadIdx.x >> 6;
    const int lo   = lane & 15;
    const int hi   = lane >> 4;
    const int n0   = blockIdx.x * 64 + wloc * 16;

    float bb4[4];
#pragma unroll
    for (int tt = 0; tt < 4; ++tt) bb4[tt] = bias[tt * 16 + lo];

    f32x4 acc[4];
#pragma unroll
    for (int tt = 0; tt < 4; ++tt) acc[tt] = (f32x4){0.f, 0.f, 0.f, 0.f};

    const bf16x8* wb = (const bf16x8*)wbS;
    const float* xrow = x + (size_t)(n0 + lo) * CIN;

#pragma unroll
    for (int kb = 0; kb < 7; ++kb) {
        union { bf16x8 b; unsigned short u[8]; } A;
        if (kb < 6 || hi == 0) {
            const float* px = xrow + kb * 32 + hi * 8;
            float4 u0 = *(const float4*)px;
            float4 u1 = *(const float4*)(px + 4);
            A.u[0] = f2bf(u0.x); A.u[1] = f2bf(u0.y);
            A.u[2] = f2bf(u0.z); A.u[3] = f2bf(u0.w);
            A.u[4] = f2bf(u1.x); A.u[5] = f2bf(u1.y);
            A.u[6] = f2bf(u1.z); A.u[7] = f2bf(u1.w);
        } else {
#pragma unroll
            for (int i = 0; i < 8; ++i) A.u[i] = 0;
        }
#pragma unroll
        for (int tt = 0; tt < 4; ++tt)
            acc[tt] = __builtin_amdgcn_mfma_f32_16x16x32_bf16(
                A.b, wb[(kb * 4 + tt) * 64 + lane], acc[tt], 0, 0, 0);
    }

    float ss[4] = {0.f, 0.f, 0.f, 0.f}, ss2[4] = {0.f, 0.f, 0.f, 0.f};
#pragma unroll
    for (int tt = 0; tt < 4; ++tt) {
        const int col = tt * 16 + lo;
#pragma unroll
        for (int r = 0; r < 4; ++r) {
            const int n = n0 + hi * 4 + r;
            float v = acc[tt][r] + bb4[tt];
            t[(size_t)n * 64 + col] = f2bf(v);
            ss[tt] += v;
            ss2[tt] += v * v;
        }
    }

#pragma unroll
    for (int tt = 0; tt < 4; ++tt) {
        ss[tt]  += __shfl_xor(ss[tt], 16);  ss[tt]  += __shfl_xor(ss[tt], 32);
        ss2[tt] += __shfl_xor(ss2[tt], 16); ss2[tt] += __shfl_xor(ss2[tt], 32);
    }
    __shared__ float ls[4][64], ls2[4][64];
    if (lo == lane) {
#pragma unroll
        for (int tt = 0; tt < 4; ++tt) {
            ls[wloc][tt * 16 + lane]  = ss[tt];
            ls2[wloc][tt * 16 + lane] = ss2[tt];
        }
    }
    __syncthreads();
    if (threadIdx.x < 64) {
        int ch = threadIdx.x;
        atomicAdd(&stats[ch],      ls[0][ch] + ls[1][ch] + ls[2][ch] + ls[3][ch]);
        atomicAdd(&stats[64 + ch], ls2[0][ch] + ls2[1][ch] + ls2[2][ch] + ls2[3][ch]);
    }
}

// fold BN into per-channel affine:  bn(v) = v*a + c
__global__ void finalize_bn(const float* __restrict__ stats,
                            const float* __restrict__ g, const float* __restrict__ b,
                            float* __restrict__ ac)
{
    int c = threadIdx.x;
    float mean = stats[c] * (1.f / NN);
    float var  = stats[64 + c] * (1.f / NN) - mean * mean;
    float rstd = rsqrtf(var + EPSV);
    float a = g[c] * rstd;
    ac[c]      = a;
    ac[64 + c] = b[c] - mean * a;
}

// ---- ln: xnb = bf16(LN(leaky?(affine(u_bf16)))) -------------------------------
template <int RELU>
__global__ __launch_bounds__(256) void ln_kernel(
    const unsigned short* __restrict__ u, const float* __restrict__ ac,
    const float* __restrict__ lng, const float* __restrict__ lnb,
    unsigned short* __restrict__ xnb)
{
    const int lane = threadIdx.x & 63;
    const int wid  = (blockIdx.x * 256 + threadIdx.x) >> 6;
    const int nw   = (gridDim.x * 256) >> 6;
    const float a  = ac[lane],  c0 = ac[64 + lane];
    const float g  = lng[lane], bl = lnb[lane];

    for (int row = wid; row < NN; row += nw) {
        float v = bf2f(u[(size_t)row * 64 + lane]);
        v = v * a + c0;
        if (RELU) v = (v > 0.f) ? v : 0.01f * v;
        float s = v;
#pragma unroll
        for (int off = 32; off > 0; off >>= 1) s += __shfl_xor(s, off);
        float mean = s * (1.f / 64.f);
        float d = v - mean;
        float s2 = d * d;
#pragma unroll
        for (int off = 32; off > 0; off >>= 1) s2 += __shfl_xor(s2, off);
        float rstd = rsqrtf(s2 * (1.f / 64.f) + EPSV);
        float o = d * rstd * g + bl;
        xnb[(size_t)row * 64 + lane] = f2bf(o);
    }
}

// ================= CSR build (graph identical for both layers) ==================
__global__ __launch_bounds__(256) void hist_kernel(
    const int* __restrict__ rowsrc, const int* __restrict__ colsrc,
    int* __restrict__ cnt)
{
    for (int i = blockIdx.x * 256 + threadIdx.x; i < EE; i += gridDim.x * 256) {
        atomicAdd(&cnt[rowsrc[i]], 1);
        atomicAdd(&cnt[NN + colsrc[i]], 1);
    }
}

__global__ __launch_bounds__(256) void scan1_kernel(
    const int* __restrict__ cnt, int* __restrict__ bsum)
{
    const int t = threadIdx.x;
    const int base = blockIdx.x * 1024 + t * 4;
    int s = cnt[base] + cnt[base + 1] + cnt[base + 2] + cnt[base + 3];
    __shared__ int sm[256];
    sm[t] = s;
    __syncthreads();
    for (int off = 1; off < 256; off <<= 1) {
        int v = (t >= off) ? sm[t - off] : 0;
        __syncthreads();
        sm[t] += v;
        __syncthreads();
    }
    if (t == 255) bsum[blockIdx.x] = sm[255];
}

__global__ __launch_bounds__(512) void scan2_kernel(
    const int* __restrict__ bsum, int* __restrict__ bpre, int* __restrict__ ptr)
{
    const int t = threadIdx.x;
    __shared__ int sm[512];
    int orig = bsum[t];
    sm[t] = orig;
    __syncthreads();
    for (int off = 1; off < 512; off <<= 1) {
        int v = (t >= off) ? sm[t - off] : 0;
        __syncthreads();
        sm[t] += v;
        __syncthreads();
    }
    bpre[t] = sm[t] - orig;
    if (t == 0) ptr[NB] = 2 * EE;
}

__global__ __launch_bounds__(256) void scan3_kernel(
    const int* __restrict__ cnt, const int* __restrict__ bpre,
    int* __restrict__ ptr, int* __restrict__ cursor)
{
    const int t = threadIdx.x;
    const int base = blockIdx.x * 1024 + t * 4;
    int c0 = cnt[base], c1 = cnt[base + 1], c2 = cnt[base + 2], c3 = cnt[base + 3];
    int tsum = c0 + c1 + c2 + c3;
    __shared__ int sm[256];
    sm[t] = tsum;
    __syncthreads();
    for (int off = 1; off < 256; off <<= 1) {
        int v = (t >= off) ? sm[t - off] : 0;
        __syncthreads();
        sm[t] += v;
        __syncthreads();
    }
    int p = bpre[blockIdx.x] + sm[t] - tsum;
    ptr[base] = p;     cursor[base] = p;     p += c0;
    ptr[base + 1] = p; cursor[base + 1] = p; p += c1;
    ptr[base + 2] = p; cursor[base + 2] = p; p += c2;
    ptr[base + 3] = p; cursor[base + 3] = p;
}

// ---- winit: 16 window cursors = ptr at window boundaries ----------------------
__global__ void winit_kernel(const int* __restrict__ ptr, int* __restrict__ wcur)
{
    int t = threadIdx.x;   // 0..15
    wcur[t] = ptr[t * 32768];
}

// ---- partA: single-scan 16-way partition into window-staged (s,dst,att) ------
// NT loads: every input line is read exactly once, coalesced -> keep out of L2
// so partA's staged write runs stay resident and combine.
__global__ __launch_bounds__(256) void partA_kernel(
    const int* __restrict__ rowsrc, const int* __restrict__ rowdst,
    const float* __restrict__ ratt,
    const int* __restrict__ colsrc, const int* __restrict__ coldst,
    const float* __restrict__ catt,
    int* __restrict__ wcur,
    long long* __restrict__ psd, float* __restrict__ patt)
{
    __shared__ int hcnt[16], hbase[16];
    const int tid = threadIdx.x;

    for (long long t0 = (long long)blockIdx.x * 1024; t0 < 2LL * EE;
         t0 += (long long)gridDim.x * 1024) {
        if (tid < 16) hcnt[tid] = 0;
        __syncthreads();

        int w[4], rank[4], dstv[4], sfl[4];
        float attv[4];
#pragma unroll
        for (int u = 0; u < 4; ++u) {
            long long i = t0 + u * 256 + tid;
            if (i < 2LL * EE) {
                bool isrow = i < EE;
                long long j = isrow ? i : i - EE;
                int s   = isrow ? __builtin_nontemporal_load(&rowsrc[j])
                                : __builtin_nontemporal_load(&colsrc[j]);
                dstv[u] = isrow ? __builtin_nontemporal_load(&rowdst[j])
                                : __builtin_nontemporal_load(&coldst[j]);
                attv[u] = isrow ? __builtin_nontemporal_load(&ratt[j])
                                : __builtin_nontemporal_load(&catt[j]);
                w[u]    = (isrow ? 0 : 8) + (s >> 15);
                sfl[u]  = (isrow ? 0 : NN) + s;
                rank[u] = atomicAdd(&hcnt[w[u]], 1);
            } else {
                w[u] = -1;
            }
        }
        __syncthreads();
        if (tid < 16) hbase[tid] = atomicAdd(&wcur[tid], hcnt[tid]);
        __syncthreads();
#pragma unroll
        for (int u = 0; u < 4; ++u) {
            if (w[u] >= 0) {
                int pos = hbase[w[u]] + rank[u];
                psd[pos]  = ((long long)sfl[u] << 32) | (unsigned int)dstv[u];
                patt[pos] = attv[u];
            }
        }
        __syncthreads();   // before hcnt reuse
    }
}

// ---- partB (XCD-pinned + NT reads): group x=bid&7 owns windows {x, x+8} -------
// NT loads keep the read-once staged stream out of L2 so the 2.1 MB dirty
// window lines stay resident until all 8 writes/line arrive -> write combining.
__global__ __launch_bounds__(256) void partB_kernel(
    const int* __restrict__ ptr,
    const long long* __restrict__ psd, const float* __restrict__ patt,
    int* __restrict__ cursor, int2* __restrict__ edges)
{
    const int x    = blockIdx.x & 7;
    const int sub  = blockIdx.x >> 3;
    const int NSUB = gridDim.x >> 3;
#pragma unroll
    for (int half = 0; half < 2; ++half) {
        const int w  = x + half * 8;
        const int lo = ptr[w * 32768];
        const int hi = (w == 15) ? 2 * EE : ptr[(w + 1) * 32768];
        for (int i = lo + sub * 256 + threadIdx.x; i < hi; i += NSUB * 256) {
            long long q = __builtin_nontemporal_load(&psd[i]);
            float    a = __builtin_nontemporal_load(&patt[i]);
            int s = (int)(q >> 32);
            int d = (int)(q & 0xffffffffLL);
            int slot = atomicAdd(&cursor[s], 1);
            edges[slot] = make_int2(d, __float_as_int(a));
        }
    }
}

// ---- pure gather, 4 concurrent streams per wave (R9-proven version) -----------
__global__ __launch_bounds__(256) void gather_kernel(
    const unsigned short* __restrict__ xnb,
    const int* __restrict__ ptr, const int2* __restrict__ edges,
    unsigned short* __restrict__ rxb, unsigned short* __restrict__ cxb,
    float2* __restrict__ attsum)
{
    const int lane = threadIdx.x & 63;
    const int wid  = (blockIdx.x * 256 + threadIdx.x) >> 6;
    const int nw   = (gridDim.x * 256) >> 6;
    const int HALF = NN / 2;

    for (int n = wid; n < HALF; n += nw) {
        const int m = n + HALF;
        const int i0 = ptr[n],      e0 = ptr[n + 1];
        const int i1 = ptr[NN + n], e1 = ptr[NN + n + 1];
        const int i2 = ptr[m],      e2 = ptr[m + 1];
        const int i3 = ptr[NN + m], e3 = ptr[NN + m + 1];
        const int len0 = e0 - i0, len1 = e1 - i1, len2 = e2 - i2, len3 = e3 - i3;
        int maxlen = max(max(len0, len1), max(len2, len3));

        float rx0 = 0.f, cx0 = 0.f, rx1 = 0.f, cx1 = 0.f;
        float ras0 = 0.f, cas0 = 0.f, ras1 = 0.f, cas1 = 0.f;

#pragma unroll 2
        for (int k = 0; k < maxlen; ++k) {
            int j0 = min(i0 + ((k < len0) ? k : 0), 2 * EE - 1);
            int j1 = min(i1 + ((k < len1) ? k : 0), 2 * EE - 1);
            int j2 = min(i2 + ((k < len2) ? k : 0), 2 * EE - 1);
            int j3 = min(i3 + ((k < len3) ? k : 0), 2 * EE - 1);
            int2 p0 = edges[j0];
            int2 p1 = edges[j1];
            int2 p2 = edges[j2];
            int2 p3 = edges[j3];
            float v0 = bf2f(xnb[(size_t)p0.x * 64 + lane]);
            float v1 = bf2f(xnb[(size_t)p1.x * 64 + lane]);
            float v2 = bf2f(xnb[(size_t)p2.x * 64 + lane]);
            float v3 = bf2f(xnb[(size_t)p3.x * 64 + lane]);
            float a0 = (k < len0) ? __int_as_float(p0.y) : 0.f;
            float a1 = (k < len1) ? __int_as_float(p1.y) : 0.f;
            float a2 = (k < len2) ? __int_as_float(p2.y) : 0.f;
            float a3 = (k < len3) ? __int_as_float(p3.y) : 0.f;
            rx0 = fmaf(v0, a0, rx0); ras0 += a0;
            cx0 = fmaf(v1, a1, cx0); cas0 += a1;
            rx1 = fmaf(v2, a2, rx1); ras1 += a2;
            cx1 = fmaf(v3, a3, cx1); cas1 += a3;
        }

        rxb[(size_t)n * 64 + lane] = f2bf(rx0);
        cxb[(size_t)n * 64 + lane] = f2bf(cx0);
        rxb[(size_t)m * 64 + lane] = f2bf(rx1);
        cxb[(size_t)m * 64 + lane] = f2bf(cx1);
        if (lane == 0) {
            attsum[n] = make_float2(ras0, cas0);
            attsum[m] = make_float2(ras1, cas1);
        }
    }
}

// ---- weight pre-swizzle into MFMA B-fragment layout (bf16) --------------------
__global__ __launch_bounds__(256) void w_convert(
    const float* __restrict__ Wrv, const float* __restrict__ Wcv,
    unsigned short* __restrict__ wbuf)
{
    int idx = blockIdx.x * 256 + threadIdx.x;   // 0..16383
    int e    = idx & 7;
    int lane = (idx >> 3) & 63;
    int t    = (idx >> 9) & 3;
    int kb   = (idx >> 11) & 1;
    int m    = (idx >> 12) & 1;
    int L    = (idx >> 13) & 1;
    const float* W = (m ? Wcv : Wrv) + L * 4096;
    float w = W[(kb * 32 + ((lane >> 4) & 3) * 8 + e) * 64 + t * 16 + (lane & 15)];
    wbuf[idx] = f2bf(w);
}

// ---- MFMA epilogue: out = bf16(xnb + rx@Wr + cx@Wc + ras·br + cas·bc) ---------
__global__ __launch_bounds__(256) void gemv_mfma(
    const unsigned short* __restrict__ rxb, const unsigned short* __restrict__ cxb,
    const unsigned short* __restrict__ xnb, const float2* __restrict__ attsum,
    const unsigned short* __restrict__ wb16,
    const float* __restrict__ br, const float* __restrict__ bc,
    unsigned short* __restrict__ out, float* __restrict__ stats)
{
    const int lane = threadIdx.x & 63;
    const int wloc = threadIdx.x >> 6;
    const int wid  = (blockIdx.x * 256 + threadIdx.x) >> 6;
    const int nw   = (gridDim.x * 256) >> 6;
    const int lo   = lane & 15;
    const int hi   = lane >> 4;

    const bf16x8* wb = (const bf16x8*)wb16;
    bf16x8 bfr[2][2][4];
#pragma unroll
    for (int m = 0; m < 2; ++m)
#pragma unroll
        for (int kb = 0; kb < 2; ++kb)
#pragma unroll
            for (int t = 0; t < 4; ++t)
                bfr[m][kb][t] = wb[((m * 2 + kb) * 4 + t) * 64 + lane];

    float brv4[4], bcv4[4];
#pragma unroll
    for (int t = 0; t < 4; ++t) {
        brv4[t] = br[t * 16 + lo];
        bcv4[t] = bc[t * 16 + lo];
    }

    float ss[4] = {0.f, 0.f, 0.f, 0.f}, ss2[4] = {0.f, 0.f, 0.f, 0.f};
    const bf16x8* ra = (const bf16x8*)rxb;
    const bf16x8* ca = (const bf16x8*)cxb;

    for (int tile = wid; tile < NN / 16; tile += nw) {
        const int n0 = tile * 16;
        const int arow = n0 + lo;
        bf16x8 a0 = ra[arow * 8 + hi];
        bf16x8 a1 = ra[arow * 8 + 4 + hi];
        bf16x8 c0 = ca[arow * 8 + hi];
        bf16x8 c1 = ca[arow * 8 + 4 + hi];
        float2 an[4];
#pragma unroll
        for (int r = 0; r < 4; ++r) an[r] = attsum[n0 + hi * 4 + r];

#pragma unroll
        for (int t = 0; t < 4; ++t) {
            f32x4 acc = {0.f, 0.f, 0.f, 0.f};
            acc = __builtin_amdgcn_mfma_f32_16x16x32_bf16(a0, bfr[0][0][t], acc, 0, 0, 0);
            acc = __builtin_amdgcn_mfma_f32_16x16x32_bf16(a1, bfr[0][1][t], acc, 0, 0, 0);
            acc = __builtin_amdgcn_mfma_f32_16x16x32_bf16(c0, bfr[1][0][t], acc, 0, 0, 0);
            acc = __builtin_amdgcn_mfma_f32_16x16x32_bf16(c1, bfr[1][1][t], acc, 0, 0, 0);
            const int col = t * 16 + lo;
#pragma unroll
            for (int r = 0; r < 4; ++r) {
                const int n = n0 + hi * 4 + r;
                float v = acc[r] + bf2f(xnb[(size_t)n * 64 + col])
                        + an[r].x * brv4[t] + an[r].y * bcv4[t];
                out[(size_t)n * 64 + col] = f2bf(v);
                ss[t] += v;
                ss2[t] += v * v;
            }
        }
    }

#pragma unroll
    for (int t = 0; t < 4; ++t) {
        ss[t]  += __shfl_xor(ss[t], 16);  ss[t]  += __shfl_xor(ss[t], 32);
        ss2[t] += __shfl_xor(ss2[t], 16); ss2[t] += __shfl_xor(ss2[t], 32);
    }
    __shared__ float ls[4][64], ls2[4][64];
    if (lo == lane) {
#pragma unroll
        for (int t = 0; t < 4; ++t) {
            ls[wloc][t * 16 + lane]  = ss[t];
            ls2[wloc][t * 16 + lane] = ss2[t];
        }
    }
    __syncthreads();
    if (threadIdx.x < 64) {
        int ch = threadIdx.x;
        atomicAdd(&stats[ch],      ls[0][ch] + ls[1][ch] + ls[2][ch] + ls[3][ch]);
        atomicAdd(&stats[64 + ch], ls2[0][ch] + ls2[1][ch] + ls2[2][ch] + ls2[3][ch]);
    }
}

// ------ fused output: affine+leaky -> logits = h@smW + b -> softmax ------------
__global__ __launch_bounds__(256) void out_kernel(
    const unsigned short* __restrict__ agg, const float* __restrict__ ac,
    const float* __restrict__ smW, const float* __restrict__ smb,
    float* __restrict__ out)
{
    __shared__ float sW[64 * 16];
    for (int i = threadIdx.x; i < 64 * 16; i += 256) sW[i] = smW[i];
    __syncthreads();
    const int j = threadIdx.x & 15;
    const int rloc = threadIdx.x >> 4;
    const float bj = smb[j];
    for (int row = blockIdx.x * 16 + rloc; row < NN; row += gridDim.x * 16) {
        float acc = bj;
#pragma unroll
        for (int k = 0; k < 64; ++k) {
            float v = bf2f(agg[(size_t)row * 64 + k]);
            v = v * ac[k] + ac[64 + k];
            v = (v > 0.f) ? v : 0.01f * v;
            acc = fmaf(v, sW[k * 16 + j], acc);
        }
        float m = acc;
#pragma unroll
        for (int off = 8; off > 0; off >>= 1) m = fmaxf(m, __shfl_xor(m, off));
        float e = expf(acc - m);
        float ssum = e;
#pragma unroll
        for (int off = 8; off > 0; off >>= 1) ssum += __shfl_xor(ssum, off);
        out[(size_t)row * 16 + j] = e / ssum;
    }
}

// ------------------------------------------------------------------------------
extern "C" void kernel_launch(void* const* d_in, const int* in_sizes, int n_in,
                              void* d_out, int out_size, void* d_ws, size_t ws_size,
                              hipStream_t stream)
{
    const float* x        = (const float*)d_in[0];
    const float* row_att  = (const float*)d_in[1];
    const float* col_att  = (const float*)d_in[2];
    const float* prelin_W = (const float*)d_in[3];
    const float* prelin_b = (const float*)d_in[4];
    const float* bn0_g    = (const float*)d_in[5];
    const float* bn0_b    = (const float*)d_in[6];
    const float* ln_g     = (const float*)d_in[7];
    const float* ln_b     = (const float*)d_in[8];
    const float* Wrv      = (const float*)d_in[9];
    const float* brv      = (const float*)d_in[10];
    const float* Wcv      = (const float*)d_in[11];
    const float* bcv      = (const float*)d_in[12];
    const float* bn_g     = (const float*)d_in[13];
    const float* bn_b     = (const float*)d_in[14];
    const float* sm_W     = (const float*)d_in[15];
    const float* sm_b     = (const float*)d_in[16];
    const int*   rowsrc   = (const int*)d_in[17];
    const int*   rowdst   = (const int*)d_in[18];
    const int*   colsrc   = (const int*)d_in[19];
    const int*   coldst   = (const int*)d_in[20];
    float* out = (float*)d_out;

    // ---- workspace layout (~180 MB) ----
    const size_t NH = (size_t)NN * 64;
    char* extra = (char*)d_ws;
    unsigned short* A   = (unsigned short*)extra; extra += NH * sizeof(short);
    unsigned short* xnb = (unsigned short*)extra; extra += NH * sizeof(short);
    unsigned short* rxb = (unsigned short*)extra; extra += NH * sizeof(short);
    unsigned short* cxb = (unsigned short*)extra; extra += NH * sizeof(short);
    float2* attsum = (float2*)extra;              extra += (size_t)NN * sizeof(float2);
    float* stats  = (float*)extra;                extra += 3 * 128 * sizeof(float);
    float* ac     = (float*)extra;                extra += 3 * 128 * sizeof(float);
    unsigned short* wbuf  = (unsigned short*)extra; extra += 16384 * sizeof(short);
    unsigned short* wbufS = (unsigned short*)extra; extra += 14336 * sizeof(short);
    int*   bsum   = (int*)extra;                  extra += 512 * sizeof(int);
    int*   bpre   = (int*)extra;                  extra += 512 * sizeof(int);
    int*   ptr    = (int*)extra;                  extra += (NB + 1) * sizeof(int);
    int*   counts = (int*)extra;                  extra += NB * sizeof(int);
    int*   cursor = (int*)extra;                  extra += NB * sizeof(int);
    int*   wcur   = (int*)extra;                  extra += 16 * sizeof(int);
    int2*  edges  = (int2*)extra;                 extra += 2 * (size_t)EE * sizeof(int2);

    // staging aliases rxb/cxb (dead until first gather; CSR build precedes it)
    long long* psd = (long long*)rxb;   // 2EE*8B = 33.5 MB = rxb exactly
    float*    patt = (float*)cxb;       // 2EE*4B = 16.8 MB (first half of cxb)

    hipMemsetAsync(stats, 0, 3 * 128 * sizeof(float), stream);
    hipMemsetAsync(counts, 0, NB * sizeof(int), stream);

    // ---- CSR build (used by both layers) ----
    hist_kernel<<<2048, 256, 0, stream>>>(rowsrc, colsrc, counts);
    scan1_kernel<<<512, 256, 0, stream>>>(counts, bsum);
    scan2_kernel<<<1, 512, 0, stream>>>(bsum, bpre, ptr);
    scan3_kernel<<<512, 256, 0, stream>>>(counts, bpre, ptr, cursor);
    winit_kernel<<<1, 16, 0, stream>>>(ptr, wcur);
    partA_kernel<<<1024, 256, 0, stream>>>(rowsrc, rowdst, row_att,
                                           colsrc, coldst, col_att,
                                           wcur, psd, patt);
    partB_kernel<<<2048, 256, 0, stream>>>(ptr, psd, patt, cursor, edges);
    w_convert<<<64, 256, 0, stream>>>(Wrv, Wcv, wbuf);
    w_convert_stem<<<56, 256, 0, stream>>>(prelin_W, wbufS);

    // ---- stem (MFMA, stats fused) ----
    stem_mfma<<<NN / 64, 256, 0, stream>>>(x, wbufS, prelin_b, A, stats);
    finalize_bn<<<1, 64, 0, stream>>>(stats, bn0_g, bn0_b, ac);

    // ---- layer 0 ----
    ln_kernel<0><<<4096, 256, 0, stream>>>(A, ac, ln_g, ln_b, xnb);
    gather_kernel<<<8192, 256, 0, stream>>>(xnb, ptr, edges, rxb, cxb, attsum);
    gemv_mfma<<<2048, 256, 0, stream>>>(rxb, cxb, xnb, attsum, wbuf,
                                        brv, bcv, A, stats + 128);
    finalize_bn<<<1, 64, 0, stream>>>(stats + 128, bn_g, bn_b, ac + 128);

    // ---- layer 1 ----
    ln_kernel<1><<<4096, 256, 0, stream>>>(A, ac + 128, ln_g + 64, ln_b + 64, xnb);
    gather_kernel<<<8192, 256, 0, stream>>>(xnb, ptr, edges, rxb, cxb, attsum);
    gemv_mfma<<<2048, 256, 0, stream>>>(rxb, cxb, xnb, attsum, wbuf + 8192,
                                        brv + 64, bcv + 64, A, stats + 256);
    finalize_bn<<<1, 64, 0, stream>>>(stats + 256, bn_g + 64, bn_b + 64, ac + 256);

    // ---- output head ----
    out_kernel<<<2048, 256, 0, stream>>>(A, ac + 256, sm_W, sm_b, out);
}

// Round 19
// 1221.911 us; speedup vs baseline: 1.1430x; 1.1430x over previous
//
#include <hip/hip_runtime.h>
#include <math.h>

#define NN   262144      // nodes
#define CIN  200         // input channels
#define EE   2097152     // edges
#define NB   (2*NN)      // flat count/ptr sections: [row | col]
#define BKN  2048        // flat-nodes per sort bucket
#define NBKT 256         // buckets
#define CAP  18176       // LDS record capacity per bucket (mean 16384, sd 128)
#define EPSV 1e-5f

typedef __bf16 bf16x8 __attribute__((ext_vector_type(8)));
typedef float  f32x4  __attribute__((ext_vector_type(4)));

__device__ __forceinline__ unsigned short f2bf(float f) {
    unsigned int u = __float_as_uint(f);
    unsigned int r = (u + 0x7fffu + ((u >> 16) & 1u)) >> 16;
    return (unsigned short)r;
}
__device__ __forceinline__ float bf2f(unsigned short u) {
    return __uint_as_float(((unsigned int)u) << 16);
}

// ---- stem weight pre-swizzle: W[200][64] fp32 -> B-frag bf16, K padded to 224 --
__global__ __launch_bounds__(256) void w_convert_stem(
    const float* __restrict__ W, unsigned short* __restrict__ wbufS)
{
    int idx = blockIdx.x * 256 + threadIdx.x;    // 0..14335
    if (idx >= 28 * 64 * 8) return;
    int e    = idx & 7;
    int lane = (idx >> 3) & 63;
    int f    = idx >> 9;          // 0..27
    int t    = f & 3;
    int kb   = f >> 2;
    int k    = kb * 32 + ((lane >> 4) & 3) * 8 + e;
    float w  = (k < CIN) ? W[k * 64 + t * 16 + (lane & 15)] : 0.f;
    wbufS[idx] = f2bf(w);
}

// ------- stem via MFMA: t = bf16(x @ W + b), fused fp32 BN stats ---------------
__global__ __launch_bounds__(256) void stem_mfma(
    const float* __restrict__ x, const unsigned short* __restrict__ wbS,
    const float* __restrict__ bias, unsigned short* __restrict__ t,
    float* __restrict__ stats)
{
    const int lane = threadIdx.x & 63;
    const int wloc = threadIdx.x >> 6;
    const int lo   = lane & 15;
    const int hi   = lane >> 4;
    const int n0   = blockIdx.x * 64 + wloc * 16;

    float bb4[4];
#pragma unroll
    for (int tt = 0; tt < 4; ++tt) bb4[tt] = bias[tt * 16 + lo];

    f32x4 acc[4];
#pragma unroll
    for (int tt = 0; tt < 4; ++tt) acc[tt] = (f32x4){0.f, 0.f, 0.f, 0.f};

    const bf16x8* wb = (const bf16x8*)wbS;
    const float* xrow = x + (size_t)(n0 + lo) * CIN;

#pragma unroll
    for (int kb = 0; kb < 7; ++kb) {
        union { bf16x8 b; unsigned short u[8]; } A;
        if (kb < 6 || hi == 0) {
            const float* px = xrow + kb * 32 + hi * 8;
            float4 u0 = *(const float4*)px;
            float4 u1 = *(const float4*)(px + 4);
            A.u[0] = f2bf(u0.x); A.u[1] = f2bf(u0.y);
            A.u[2] = f2bf(u0.z); A.u[3] = f2bf(u0.w);
            A.u[4] = f2bf(u1.x); A.u[5] = f2bf(u1.y);
            A.u[6] = f2bf(u1.z); A.u[7] = f2bf(u1.w);
        } else {
#pragma unroll
            for (int i = 0; i < 8; ++i) A.u[i] = 0;
        }
#pragma unroll
        for (int tt = 0; tt < 4; ++tt)
            acc[tt] = __builtin_amdgcn_mfma_f32_16x16x32_bf16(
                A.b, wb[(kb * 4 + tt) * 64 + lane], acc[tt], 0, 0, 0);
    }

    float ss[4] = {0.f, 0.f, 0.f, 0.f}, ss2[4] = {0.f, 0.f, 0.f, 0.f};
#pragma unroll
    for (int tt = 0; tt < 4; ++tt) {
        const int col = tt * 16 + lo;
#pragma unroll
        for (int r = 0; r < 4; ++r) {
            const int n = n0 + hi * 4 + r;
            float v = acc[tt][r] + bb4[tt];
            t[(size_t)n * 64 + col] = f2bf(v);
            ss[tt] += v;
            ss2[tt] += v * v;
        }
    }

#pragma unroll
    for (int tt = 0; tt < 4; ++tt) {
        ss[tt]  += __shfl_xor(ss[tt], 16);  ss[tt]  += __shfl_xor(ss[tt], 32);
        ss2[tt] += __shfl_xor(ss2[tt], 16); ss2[tt] += __shfl_xor(ss2[tt], 32);
    }
    __shared__ float ls[4][64], ls2[4][64];
    if (lo == lane) {
#pragma unroll
        for (int tt = 0; tt < 4; ++tt) {
            ls[wloc][tt * 16 + lane]  = ss[tt];
            ls2[wloc][tt * 16 + lane] = ss2[tt];
        }
    }
    __syncthreads();
    if (threadIdx.x < 64) {
        int ch = threadIdx.x;
        atomicAdd(&stats[ch],      ls[0][ch] + ls[1][ch] + ls[2][ch] + ls[3][ch]);
        atomicAdd(&stats[64 + ch], ls2[0][ch] + ls2[1][ch] + ls2[2][ch] + ls2[3][ch]);
    }
}

// fold BN into per-channel affine:  bn(v) = v*a + c
__global__ void finalize_bn(const float* __restrict__ stats,
                            const float* __restrict__ g, const float* __restrict__ b,
                            float* __restrict__ ac)
{
    int c = threadIdx.x;
    float mean = stats[c] * (1.f / NN);
    float var  = stats[64 + c] * (1.f / NN) - mean * mean;
    float rstd = rsqrtf(var + EPSV);
    float a = g[c] * rstd;
    ac[c]      = a;
    ac[64 + c] = b[c] - mean * a;
}

// ---- ln: xnb = bf16(LN(leaky?(affine(u_bf16)))) -------------------------------
template <int RELU>
__global__ __launch_bounds__(256) void ln_kernel(
    const unsigned short* __restrict__ u, const float* __restrict__ ac,
    const float* __restrict__ lng, const float* __restrict__ lnb,
    unsigned short* __restrict__ xnb)
{
    const int lane = threadIdx.x & 63;
    const int wid  = (blockIdx.x * 256 + threadIdx.x) >> 6;
    const int nw   = (gridDim.x * 256) >> 6;
    const float a  = ac[lane],  c0 = ac[64 + lane];
    const float g  = lng[lane], bl = lnb[lane];

    for (int row = wid; row < NN; row += nw) {
        float v = bf2f(u[(size_t)row * 64 + lane]);
        v = v * a + c0;
        if (RELU) v = (v > 0.f) ? v : 0.01f * v;
        float s = v;
#pragma unroll
        for (int off = 32; off > 0; off >>= 1) s += __shfl_xor(s, off);
        float mean = s * (1.f / 64.f);
        float d = v - mean;
        float s2 = d * d;
#pragma unroll
        for (int off = 32; off > 0; off >>= 1) s2 += __shfl_xor(s2, off);
        float rstd = rsqrtf(s2 * (1.f / 64.f) + EPSV);
        float o = d * rstd * g + bl;
        xnb[(size_t)row * 64 + lane] = f2bf(o);
    }
}

// ================= CSR build (graph identical for both layers) ==================
__global__ __launch_bounds__(256) void hist_kernel(
    const int* __restrict__ rowsrc, const int* __restrict__ colsrc,
    int* __restrict__ cnt)
{
    for (int i = blockIdx.x * 256 + threadIdx.x; i < EE; i += gridDim.x * 256) {
        atomicAdd(&cnt[rowsrc[i]], 1);
        atomicAdd(&cnt[NN + colsrc[i]], 1);
    }
}

__global__ __launch_bounds__(256) void scan1_kernel(
    const int* __restrict__ cnt, int* __restrict__ bsum)
{
    const int t = threadIdx.x;
    const int base = blockIdx.x * 1024 + t * 4;
    int s = cnt[base] + cnt[base + 1] + cnt[base + 2] + cnt[base + 3];
    __shared__ int sm[256];
    sm[t] = s;
    __syncthreads();
    for (int off = 1; off < 256; off <<= 1) {
        int v = (t >= off) ? sm[t - off] : 0;
        __syncthreads();
        sm[t] += v;
        __syncthreads();
    }
    if (t == 255) bsum[blockIdx.x] = sm[255];
}

__global__ __launch_bounds__(512) void scan2_kernel(
    const int* __restrict__ bsum, int* __restrict__ bpre, int* __restrict__ ptr)
{
    const int t = threadIdx.x;
    __shared__ int sm[512];
    int orig = bsum[t];
    sm[t] = orig;
    __syncthreads();
    for (int off = 1; off < 512; off <<= 1) {
        int v = (t >= off) ? sm[t - off] : 0;
        __syncthreads();
        sm[t] += v;
        __syncthreads();
    }
    bpre[t] = sm[t] - orig;
    if (t == 0) ptr[NB] = 2 * EE;
}

__global__ __launch_bounds__(256) void scan3_kernel(
    const int* __restrict__ cnt, const int* __restrict__ bpre,
    int* __restrict__ ptr, int* __restrict__ cursor)
{
    const int t = threadIdx.x;
    const int base = blockIdx.x * 1024 + t * 4;
    int c0 = cnt[base], c1 = cnt[base + 1], c2 = cnt[base + 2], c3 = cnt[base + 3];
    int tsum = c0 + c1 + c2 + c3;
    __shared__ int sm[256];
    sm[t] = tsum;
    __syncthreads();
    for (int off = 1; off < 256; off <<= 1) {
        int v = (t >= off) ? sm[t - off] : 0;
        __syncthreads();
        sm[t] += v;
        __syncthreads();
    }
    int p = bpre[blockIdx.x] + sm[t] - tsum;
    ptr[base] = p;     cursor[base] = p;     p += c0;
    ptr[base + 1] = p; cursor[base + 1] = p; p += c1;
    ptr[base + 2] = p; cursor[base + 2] = p; p += c2;
    ptr[base + 3] = p; cursor[base + 3] = p;
}

// ---- winit: 256 bucket cursors = ptr at bucket boundaries ---------------------
__global__ void winit_kernel(const int* __restrict__ ptr, int* __restrict__ wcur)
{
    int t = threadIdx.x;   // 0..255
    wcur[t] = ptr[t * BKN];
}

// ---- partA: single-scan 256-way partition into bucket-staged (s,dst,att) ------
__global__ __launch_bounds__(256) void partA_kernel(
    const int* __restrict__ rowsrc, const int* __restrict__ rowdst,
    const float* __restrict__ ratt,
    const int* __restrict__ colsrc, const int* __restrict__ coldst,
    const float* __restrict__ catt,
    int* __restrict__ wcur,
    long long* __restrict__ psd, float* __restrict__ patt)
{
    __shared__ int hcnt[NBKT], hbase[NBKT];
    const int tid = threadIdx.x;

    for (long long t0 = (long long)blockIdx.x * 1024; t0 < 2LL * EE;
         t0 += (long long)gridDim.x * 1024) {
        hcnt[tid] = 0;
        __syncthreads();

        int w[4], rank[4], dstv[4], sfl[4];
        float attv[4];
#pragma unroll
        for (int u = 0; u < 4; ++u) {
            long long i = t0 + u * 256 + tid;
            if (i < 2LL * EE) {
                bool isrow = i < EE;
                long long j = isrow ? i : i - EE;
                int s   = isrow ? __builtin_nontemporal_load(&rowsrc[j])
                                : __builtin_nontemporal_load(&colsrc[j]);
                dstv[u] = isrow ? __builtin_nontemporal_load(&rowdst[j])
                                : __builtin_nontemporal_load(&coldst[j]);
                attv[u] = isrow ? __builtin_nontemporal_load(&ratt[j])
                                : __builtin_nontemporal_load(&catt[j]);
                sfl[u]  = (isrow ? 0 : NN) + s;
                w[u]    = sfl[u] >> 11;           // bucket of 2048 flat-nodes
                rank[u] = atomicAdd(&hcnt[w[u]], 1);
            } else {
                w[u] = -1;
            }
        }
        __syncthreads();
        hbase[tid] = atomicAdd(&wcur[tid], hcnt[tid]);
        __syncthreads();
#pragma unroll
        for (int u = 0; u < 4; ++u) {
            if (w[u] >= 0) {
                int pos = hbase[w[u]] + rank[u];
                psd[pos]  = ((long long)sfl[u] << 32) | (unsigned int)dstv[u];
                patt[pos] = attv[u];
            }
        }
        __syncthreads();   // before hcnt reuse
    }
}

// ---- partB_lds: per-bucket LDS counting sort -> sequential full-line writes ---
// Writes leave the CU as a sequential stream (no dependence on L2 combining).
// LDS: lcnt 8KB + lrec 142KB + sm 1KB = 154.6KB (fits 160KB with margin).
__global__ __launch_bounds__(256) void partB_lds(
    const int* __restrict__ ptr,
    const long long* __restrict__ psd, const float* __restrict__ patt,
    int2* __restrict__ edges)
{
    __shared__ int lcnt[BKN];          // counts -> (after scan) cursor
    __shared__ long long lrec[CAP];    // sorted records
    __shared__ int sm[256];
    const int tid  = threadIdx.x;
    const int b    = blockIdx.x;
    const int nb0  = b * BKN;
    const int base = ptr[nb0];
    const int end  = ptr[nb0 + BKN];   // b=255 -> ptr[NB] = 2E
    const int cnt  = end - base;

    for (int i = tid; i < BKN; i += 256) lcnt[i] = 0;
    __syncthreads();

    // pass1: per-node counts
    for (int i = tid; i < cnt; i += 256) {
        int s = (int)(psd[base + i] >> 32);
        atomicAdd(&lcnt[s - nb0], 1);
    }
    __syncthreads();

    // pass2: block-exclusive scan of 2048 counts (8 per thread); write offsets
    // back into lcnt (each thread reads then overwrites only its own 8 slots)
    int loc[8], tsum = 0;
#pragma unroll
    for (int j = 0; j < 8; ++j) { loc[j] = lcnt[tid * 8 + j]; tsum += loc[j]; }
    sm[tid] = tsum;
    __syncthreads();
    for (int off = 1; off < 256; off <<= 1) {
        int v = (tid >= off) ? sm[tid - off] : 0;
        __syncthreads();
        sm[tid] += v;
        __syncthreads();
    }
    int run = sm[tid] - tsum;
#pragma unroll
    for (int j = 0; j < 8; ++j) { lcnt[tid * 8 + j] = run; run += loc[j]; }
    __syncthreads();

    // pass3: scatter records into LDS (spill path for impossible overflow)
    for (int i = tid; i < cnt; i += 256) {
        long long q = psd[base + i];
        float    a = patt[base + i];
        int s = (int)(q >> 32);
        int d = (int)(q & 0xffffffffLL);
        int off = atomicAdd(&lcnt[s - nb0], 1);
        long long rec = ((long long)__float_as_int(a) << 32) | (unsigned int)d;
        if (off < CAP) lrec[off] = rec;
        else edges[base + off] = make_int2(d, __float_as_int(a));
    }
    __syncthreads();

    // pass4: sequential coalesced write of sorted records
    const int lim = (cnt < CAP) ? cnt : CAP;
    for (int i = tid; i < lim; i += 256) {
        long long rec = lrec[i];
        edges[base + i] = make_int2((int)(rec & 0xffffffffLL), (int)(rec >> 32));
    }
}

// ---- pure gather, 4 concurrent streams per wave (R9-proven version) -----------
__global__ __launch_bounds__(256) void gather_kernel(
    const unsigned short* __restrict__ xnb,
    const int* __restrict__ ptr, const int2* __restrict__ edges,
    unsigned short* __restrict__ rxb, unsigned short* __restrict__ cxb,
    float2* __restrict__ attsum)
{
    const int lane = threadIdx.x & 63;
    const int wid  = (blockIdx.x * 256 + threadIdx.x) >> 6;
    const int nw   = (gridDim.x * 256) >> 6;
    const int HALF = NN / 2;

    for (int n = wid; n < HALF; n += nw) {
        const int m = n + HALF;
        const int i0 = ptr[n],      e0 = ptr[n + 1];
        const int i1 = ptr[NN + n], e1 = ptr[NN + n + 1];
        const int i2 = ptr[m],      e2 = ptr[m + 1];
        const int i3 = ptr[NN + m], e3 = ptr[NN + m + 1];
        const int len0 = e0 - i0, len1 = e1 - i1, len2 = e2 - i2, len3 = e3 - i3;
        int maxlen = max(max(len0, len1), max(len2, len3));

        float rx0 = 0.f, cx0 = 0.f, rx1 = 0.f, cx1 = 0.f;
        float ras0 = 0.f, cas0 = 0.f, ras1 = 0.f, cas1 = 0.f;

#pragma unroll 2
        for (int k = 0; k < maxlen; ++k) {
            int j0 = min(i0 + ((k < len0) ? k : 0), 2 * EE - 1);
            int j1 = min(i1 + ((k < len1) ? k : 0), 2 * EE - 1);
            int j2 = min(i2 + ((k < len2) ? k : 0), 2 * EE - 1);
            int j3 = min(i3 + ((k < len3) ? k : 0), 2 * EE - 1);
            int2 p0 = edges[j0];
            int2 p1 = edges[j1];
            int2 p2 = edges[j2];
            int2 p3 = edges[j3];
            float v0 = bf2f(xnb[(size_t)p0.x * 64 + lane]);
            float v1 = bf2f(xnb[(size_t)p1.x * 64 + lane]);
            float v2 = bf2f(xnb[(size_t)p2.x * 64 + lane]);
            float v3 = bf2f(xnb[(size_t)p3.x * 64 + lane]);
            float a0 = (k < len0) ? __int_as_float(p0.y) : 0.f;
            float a1 = (k < len1) ? __int_as_float(p1.y) : 0.f;
            float a2 = (k < len2) ? __int_as_float(p2.y) : 0.f;
            float a3 = (k < len3) ? __int_as_float(p3.y) : 0.f;
            rx0 = fmaf(v0, a0, rx0); ras0 += a0;
            cx0 = fmaf(v1, a1, cx0); cas0 += a1;
            rx1 = fmaf(v2, a2, rx1); ras1 += a2;
            cx1 = fmaf(v3, a3, cx1); cas1 += a3;
        }

        rxb[(size_t)n * 64 + lane] = f2bf(rx0);
        cxb[(size_t)n * 64 + lane] = f2bf(cx0);
        rxb[(size_t)m * 64 + lane] = f2bf(rx1);
        cxb[(size_t)m * 64 + lane] = f2bf(cx1);
        if (lane == 0) {
            attsum[n] = make_float2(ras0, cas0);
            attsum[m] = make_float2(ras1, cas1);
        }
    }
}

// ---- weight pre-swizzle into MFMA B-fragment layout (bf16) --------------------
__global__ __launch_bounds__(256) void w_convert(
    const float* __restrict__ Wrv, const float* __restrict__ Wcv,
    unsigned short* __restrict__ wbuf)
{
    int idx = blockIdx.x * 256 + threadIdx.x;   // 0..16383
    int e    = idx & 7;
    int lane = (idx >> 3) & 63;
    int t    = (idx >> 9) & 3;
    int kb   = (idx >> 11) & 1;
    int m    = (idx >> 12) & 1;
    int L    = (idx >> 13) & 1;
    const float* W = (m ? Wcv : Wrv) + L * 4096;
    float w = W[(kb * 32 + ((lane >> 4) & 3) * 8 + e) * 64 + t * 16 + (lane & 15)];
    wbuf[idx] = f2bf(w);
}

// ---- MFMA epilogue: out = bf16(xnb + rx@Wr + cx@Wc + ras·br + cas·bc) ---------
__global__ __launch_bounds__(256) void gemv_mfma(
    const unsigned short* __restrict__ rxb, const unsigned short* __restrict__ cxb,
    const unsigned short* __restrict__ xnb, const float2* __restrict__ attsum,
    const unsigned short* __restrict__ wb16,
    const float* __restrict__ br, const float* __restrict__ bc,
    unsigned short* __restrict__ out, float* __restrict__ stats)
{
    const int lane = threadIdx.x & 63;
    const int wloc = threadIdx.x >> 6;
    const int wid  = (blockIdx.x * 256 + threadIdx.x) >> 6;
    const int nw   = (gridDim.x * 256) >> 6;
    const int lo   = lane & 15;
    const int hi   = lane >> 4;

    const bf16x8* wb = (const bf16x8*)wb16;
    bf16x8 bfr[2][2][4];
#pragma unroll
    for (int m = 0; m < 2; ++m)
#pragma unroll
        for (int kb = 0; kb < 2; ++kb)
#pragma unroll
            for (int t = 0; t < 4; ++t)
                bfr[m][kb][t] = wb[((m * 2 + kb) * 4 + t) * 64 + lane];

    float brv4[4], bcv4[4];
#pragma unroll
    for (int t = 0; t < 4; ++t) {
        brv4[t] = br[t * 16 + lo];
        bcv4[t] = bc[t * 16 + lo];
    }

    float ss[4] = {0.f, 0.f, 0.f, 0.f}, ss2[4] = {0.f, 0.f, 0.f, 0.f};
    const bf16x8* ra = (const bf16x8*)rxb;
    const bf16x8* ca = (const bf16x8*)cxb;

    for (int tile = wid; tile < NN / 16; tile += nw) {
        const int n0 = tile * 16;
        const int arow = n0 + lo;
        bf16x8 a0 = ra[arow * 8 + hi];
        bf16x8 a1 = ra[arow * 8 + 4 + hi];
        bf16x8 c0 = ca[arow * 8 + hi];
        bf16x8 c1 = ca[arow * 8 + 4 + hi];
        float2 an[4];
#pragma unroll
        for (int r = 0; r < 4; ++r) an[r] = attsum[n0 + hi * 4 + r];

#pragma unroll
        for (int t = 0; t < 4; ++t) {
            f32x4 acc = {0.f, 0.f, 0.f, 0.f};
            acc = __builtin_amdgcn_mfma_f32_16x16x32_bf16(a0, bfr[0][0][t], acc, 0, 0, 0);
            acc = __builtin_amdgcn_mfma_f32_16x16x32_bf16(a1, bfr[0][1][t], acc, 0, 0, 0);
            acc = __builtin_amdgcn_mfma_f32_16x16x32_bf16(c0, bfr[1][0][t], acc, 0, 0, 0);
            acc = __builtin_amdgcn_mfma_f32_16x16x32_bf16(c1, bfr[1][1][t], acc, 0, 0, 0);
            const int col = t * 16 + lo;
#pragma unroll
            for (int r = 0; r < 4; ++r) {
                const int n = n0 + hi * 4 + r;
                float v = acc[r] + bf2f(xnb[(size_t)n * 64 + col])
                        + an[r].x * brv4[t] + an[r].y * bcv4[t];
                out[(size_t)n * 64 + col] = f2bf(v);
                ss[t] += v;
                ss2[t] += v * v;
            }
        }
    }

#pragma unroll
    for (int t = 0; t < 4; ++t) {
        ss[t]  += __shfl_xor(ss[t], 16);  ss[t]  += __shfl_xor(ss[t], 32);
        ss2[t] += __shfl_xor(ss2[t], 16); ss2[t] += __shfl_xor(ss2[t], 32);
    }
    __shared__ float ls[4][64], ls2[4][64];
    if (lo == lane) {
#pragma unroll
        for (int t = 0; t < 4; ++t) {
            ls[wloc][t * 16 + lane]  = ss[t];
            ls2[wloc][t * 16 + lane] = ss2[t];
        }
    }
    __syncthreads();
    if (threadIdx.x < 64) {
        int ch = threadIdx.x;
        atomicAdd(&stats[ch],      ls[0][ch] + ls[1][ch] + ls[2][ch] + ls[3][ch]);
        atomicAdd(&stats[64 + ch], ls2[0][ch] + ls2[1][ch] + ls2[2][ch] + ls2[3][ch]);
    }
}

// ------ fused output: affine+leaky -> logits = h@smW + b -> softmax ------------
__global__ __launch_bounds__(256) void out_kernel(
    const unsigned short* __restrict__ agg, const float* __restrict__ ac,
    const float* __restrict__ smW, const float* __restrict__ smb,
    float* __restrict__ out)
{
    __shared__ float sW[64 * 16];
    for (int i = threadIdx.x; i < 64 * 16; i += 256) sW[i] = smW[i];
    __syncthreads();
    const int j = threadIdx.x & 15;
    const int rloc = threadIdx.x >> 4;
    const float bj = smb[j];
    for (int row = blockIdx.x * 16 + rloc; row < NN; row += gridDim.x * 16) {
        float acc = bj;
#pragma unroll
        for (int k = 0; k < 64; ++k) {
            float v = bf2f(agg[(size_t)row * 64 + k]);
            v = v * ac[k] + ac[64 + k];
            v = (v > 0.f) ? v : 0.01f * v;
            acc = fmaf(v, sW[k * 16 + j], acc);
        }
        float m = acc;
#pragma unroll
        for (int off = 8; off > 0; off >>= 1) m = fmaxf(m, __shfl_xor(m, off));
        float e = expf(acc - m);
        float ssum = e;
#pragma unroll
        for (int off = 8; off > 0; off >>= 1) ssum += __shfl_xor(ssum, off);
        out[(size_t)row * 16 + j] = e / ssum;
    }
}

// ------------------------------------------------------------------------------
extern "C" void kernel_launch(void* const* d_in, const int* in_sizes, int n_in,
                              void* d_out, int out_size, void* d_ws, size_t ws_size,
                              hipStream_t stream)
{
    const float* x        = (const float*)d_in[0];
    const float* row_att  = (const float*)d_in[1];
    const float* col_att  = (const float*)d_in[2];
    const float* prelin_W = (const float*)d_in[3];
    const float* prelin_b = (const float*)d_in[4];
    const float* bn0_g    = (const float*)d_in[5];
    const float* bn0_b    = (const float*)d_in[6];
    const float* ln_g     = (const float*)d_in[7];
    const float* ln_b     = (const float*)d_in[8];
    const float* Wrv      = (const float*)d_in[9];
    const float* brv      = (const float*)d_in[10];
    const float* Wcv      = (const float*)d_in[11];
    const float* bcv      = (const float*)d_in[12];
    const float* bn_g     = (const float*)d_in[13];
    const float* bn_b     = (const float*)d_in[14];
    const float* sm_W     = (const float*)d_in[15];
    const float* sm_b     = (const float*)d_in[16];
    const int*   rowsrc   = (const int*)d_in[17];
    const int*   rowdst   = (const int*)d_in[18];
    const int*   colsrc   = (const int*)d_in[19];
    const int*   coldst   = (const int*)d_in[20];
    float* out = (float*)d_out;

    // ---- workspace layout (~180 MB) ----
    const size_t NH = (size_t)NN * 64;
    char* extra = (char*)d_ws;
    unsigned short* A   = (unsigned short*)extra; extra += NH * sizeof(short);
    unsigned short* xnb = (unsigned short*)extra; extra += NH * sizeof(short);
    unsigned short* rxb = (unsigned short*)extra; extra += NH * sizeof(short);
    unsigned short* cxb = (unsigned short*)extra; extra += NH * sizeof(short);
    float2* attsum = (float2*)extra;              extra += (size_t)NN * sizeof(float2);
    float* stats  = (float*)extra;                extra += 3 * 128 * sizeof(float);
    float* ac     = (float*)extra;                extra += 3 * 128 * sizeof(float);
    unsigned short* wbuf  = (unsigned short*)extra; extra += 16384 * sizeof(short);
    unsigned short* wbufS = (unsigned short*)extra; extra += 14336 * sizeof(short);
    int*   bsum   = (int*)extra;                  extra += 512 * sizeof(int);
    int*   bpre   = (int*)extra;                  extra += 512 * sizeof(int);
    int*   ptr    = (int*)extra;                  extra += (NB + 1) * sizeof(int);
    int*   counts = (int*)extra;                  extra += NB * sizeof(int);
    int*   cursor = (int*)extra;                  extra += NB * sizeof(int);
    int*   wcur   = (int*)extra;                  extra += NBKT * sizeof(int);
    int2*  edges  = (int2*)extra;                 extra += 2 * (size_t)EE * sizeof(int2);

    // staging aliases rxb/cxb (dead until first gather; CSR build precedes it)
    long long* psd = (long long*)rxb;   // 2EE*8B = 33.5 MB = rxb exactly
    float*    patt = (float*)cxb;       // 2EE*4B = 16.8 MB (first half of cxb)

    hipMemsetAsync(stats, 0, 3 * 128 * sizeof(float), stream);
    hipMemsetAsync(counts, 0, NB * sizeof(int), stream);

    // ---- CSR build (used by both layers) ----
    hist_kernel<<<2048, 256, 0, stream>>>(rowsrc, colsrc, counts);
    scan1_kernel<<<512, 256, 0, stream>>>(counts, bsum);
    scan2_kernel<<<1, 512, 0, stream>>>(bsum, bpre, ptr);
    scan3_kernel<<<512, 256, 0, stream>>>(counts, bpre, ptr, cursor);
    winit_kernel<<<1, 256, 0, stream>>>(ptr, wcur);
    partA_kernel<<<1024, 256, 0, stream>>>(rowsrc, rowdst, row_att,
                                           colsrc, coldst, col_att,
                                           wcur, psd, patt);
    partB_lds<<<NBKT, 256, 0, stream>>>(ptr, psd, patt, edges);
    w_convert<<<64, 256, 0, stream>>>(Wrv, Wcv, wbuf);
    w_convert_stem<<<56, 256, 0, stream>>>(prelin_W, wbufS);

    // ---- stem (MFMA, stats fused) ----
    stem_mfma<<<NN / 64, 256, 0, stream>>>(x, wbufS, prelin_b, A, stats);
    finalize_bn<<<1, 64, 0, stream>>>(stats, bn0_g, bn0_b, ac);

    // ---- layer 0 ----
    ln_kernel<0><<<4096, 256, 0, stream>>>(A, ac, ln_g, ln_b, xnb);
    gather_kernel<<<8192, 256, 0, stream>>>(xnb, ptr, edges, rxb, cxb, attsum);
    gemv_mfma<<<2048, 256, 0, stream>>>(rxb, cxb, xnb, attsum, wbuf,
                                        brv, bcv, A, stats + 128);
    finalize_bn<<<1, 64, 0, stream>>>(stats + 128, bn_g, bn_b, ac + 128);

    // ---- layer 1 ----
    ln_kernel<1><<<4096, 256, 0, stream>>>(A, ac + 128, ln_g + 64, ln_b + 64, xnb);
    gather_kernel<<<8192, 256, 0, stream>>>(xnb, ptr, edges, rxb, cxb, attsum);
    gemv_mfma<<<2048, 256, 0, stream>>>(rxb, cxb, xnb, attsum, wbuf + 8192,
                                        brv + 64, bcv + 64, A, stats + 256);
    finalize_bn<<<1, 64, 0, stream>>>(stats + 256, bn_g + 64, bn_b + 64, ac + 256);

    // ---- output head ----
    out_kernel<<<2048, 256, 0, stream>>>(A, ac + 256, sm_W, sm_b, out);
}

// Round 20
// 1051.378 us; speedup vs baseline: 1.3283x; 1.1622x over previous
//
#include <hip/hip_runtime.h>
#include <math.h>

#define NN   262144      // nodes
#define CIN  200         // input channels
#define EE   2097152     // edges
#define NB   (2*NN)      // flat count/ptr sections: [row | col]
#define BKN  2048        // flat-nodes per sort bucket
#define NBKT 256         // buckets
#define CAP  18176       // LDS record capacity per bucket (mean 16384, sd 128)
#define EPSV 1e-5f

typedef __bf16 bf16x8 __attribute__((ext_vector_type(8)));
typedef float  f32x4  __attribute__((ext_vector_type(4)));

__device__ __forceinline__ unsigned short f2bf(float f) {
    unsigned int u = __float_as_uint(f);
    unsigned int r = (u + 0x7fffu + ((u >> 16) & 1u)) >> 16;
    return (unsigned short)r;
}
__device__ __forceinline__ float bf2f(unsigned short u) {
    return __uint_as_float(((unsigned int)u) << 16);
}

// ---- combined weight pre-swizzle: layer weights + stem weights ---------------
__global__ __launch_bounds__(256) void w_all(
    const float* __restrict__ Wrv, const float* __restrict__ Wcv,
    const float* __restrict__ Wstem,
    unsigned short* __restrict__ wbuf, unsigned short* __restrict__ wbufS)
{
    int idx = blockIdx.x * 256 + threadIdx.x;
    if (idx < 16384) {
        int e    = idx & 7;
        int lane = (idx >> 3) & 63;
        int t    = (idx >> 9) & 3;
        int kb   = (idx >> 11) & 1;
        int m    = (idx >> 12) & 1;
        int L    = (idx >> 13) & 1;
        const float* W = (m ? Wcv : Wrv) + L * 4096;
        float w = W[(kb * 32 + ((lane >> 4) & 3) * 8 + e) * 64 + t * 16 + (lane & 15)];
        wbuf[idx] = f2bf(w);
    } else if (idx < 16384 + 14336) {
        int j    = idx - 16384;
        int e    = j & 7;
        int lane = (j >> 3) & 63;
        int f    = j >> 9;          // 0..27
        int t    = f & 3;
        int kb   = f >> 2;
        int k    = kb * 32 + ((lane >> 4) & 3) * 8 + e;
        float w  = (k < CIN) ? Wstem[k * 64 + t * 16 + (lane & 15)] : 0.f;
        wbufS[j] = f2bf(w);
    }
}

// ------- stem via MFMA: t = bf16(x @ W + b), fused fp32 BN stats ---------------
__global__ __launch_bounds__(256) void stem_mfma(
    const float* __restrict__ x, const unsigned short* __restrict__ wbS,
    const float* __restrict__ bias, unsigned short* __restrict__ t,
    float* __restrict__ stats)
{
    const int lane = threadIdx.x & 63;
    const int wloc = threadIdx.x >> 6;
    const int lo   = lane & 15;
    const int hi   = lane >> 4;
    const int n0   = blockIdx.x * 64 + wloc * 16;

    float bb4[4];
#pragma unroll
    for (int tt = 0; tt < 4; ++tt) bb4[tt] = bias[tt * 16 + lo];

    f32x4 acc[4];
#pragma unroll
    for (int tt = 0; tt < 4; ++tt) acc[tt] = (f32x4){0.f, 0.f, 0.f, 0.f};

    const bf16x8* wb = (const bf16x8*)wbS;
    const float* xrow = x + (size_t)(n0 + lo) * CIN;

#pragma unroll
    for (int kb = 0; kb < 7; ++kb) {
        union { bf16x8 b; unsigned short u[8]; } A;
        if (kb < 6 || hi == 0) {
            const float* px = xrow + kb * 32 + hi * 8;
            float4 u0 = *(const float4*)px;
            float4 u1 = *(const float4*)(px + 4);
            A.u[0] = f2bf(u0.x); A.u[1] = f2bf(u0.y);
            A.u[2] = f2bf(u0.z); A.u[3] = f2bf(u0.w);
            A.u[4] = f2bf(u1.x); A.u[5] = f2bf(u1.y);
            A.u[6] = f2bf(u1.z); A.u[7] = f2bf(u1.w);
        } else {
#pragma unroll
            for (int i = 0; i < 8; ++i) A.u[i] = 0;
        }
#pragma unroll
        for (int tt = 0; tt < 4; ++tt)
            acc[tt] = __builtin_amdgcn_mfma_f32_16x16x32_bf16(
                A.b, wb[(kb * 4 + tt) * 64 + lane], acc[tt], 0, 0, 0);
    }

    float ss[4] = {0.f, 0.f, 0.f, 0.f}, ss2[4] = {0.f, 0.f, 0.f, 0.f};
#pragma unroll
    for (int tt = 0; tt < 4; ++tt) {
        const int col = tt * 16 + lo;
#pragma unroll
        for (int r = 0; r < 4; ++r) {
            const int n = n0 + hi * 4 + r;
            float v = acc[tt][r] + bb4[tt];
            t[(size_t)n * 64 + col] = f2bf(v);
            ss[tt] += v;
            ss2[tt] += v * v;
        }
    }

#pragma unroll
    for (int tt = 0; tt < 4; ++tt) {
        ss[tt]  += __shfl_xor(ss[tt], 16);  ss[tt]  += __shfl_xor(ss[tt], 32);
        ss2[tt] += __shfl_xor(ss2[tt], 16); ss2[tt] += __shfl_xor(ss2[tt], 32);
    }
    __shared__ float ls[4][64], ls2[4][64];
    if (lo == lane) {
#pragma unroll
        for (int tt = 0; tt < 4; ++tt) {
            ls[wloc][tt * 16 + lane]  = ss[tt];
            ls2[wloc][tt * 16 + lane] = ss2[tt];
        }
    }
    __syncthreads();
    if (threadIdx.x < 64) {
        int ch = threadIdx.x;
        atomicAdd(&stats[ch],      ls[0][ch] + ls[1][ch] + ls[2][ch] + ls[3][ch]);
        atomicAdd(&stats[64 + ch], ls2[0][ch] + ls2[1][ch] + ls2[2][ch] + ls2[3][ch]);
    }
}

// fold BN into per-channel affine:  bn(v) = v*a + c
__global__ void finalize_bn(const float* __restrict__ stats,
                            const float* __restrict__ g, const float* __restrict__ b,
                            float* __restrict__ ac)
{
    int c = threadIdx.x;
    float mean = stats[c] * (1.f / NN);
    float var  = stats[64 + c] * (1.f / NN) - mean * mean;
    float rstd = rsqrtf(var + EPSV);
    float a = g[c] * rstd;
    ac[c]      = a;
    ac[64 + c] = b[c] - mean * a;
}

// ---- ln: xnb = bf16(LN(leaky?(affine(u_bf16)))) -------------------------------
template <int RELU>
__global__ __launch_bounds__(256) void ln_kernel(
    const unsigned short* __restrict__ u, const float* __restrict__ ac,
    const float* __restrict__ lng, const float* __restrict__ lnb,
    unsigned short* __restrict__ xnb)
{
    const int lane = threadIdx.x & 63;
    const int wid  = (blockIdx.x * 256 + threadIdx.x) >> 6;
    const int nw   = (gridDim.x * 256) >> 6;
    const float a  = ac[lane],  c0 = ac[64 + lane];
    const float g  = lng[lane], bl = lnb[lane];

    for (int row = wid; row < NN; row += nw) {
        float v = bf2f(u[(size_t)row * 64 + lane]);
        v = v * a + c0;
        if (RELU) v = (v > 0.f) ? v : 0.01f * v;
        float s = v;
#pragma unroll
        for (int off = 32; off > 0; off >>= 1) s += __shfl_xor(s, off);
        float mean = s * (1.f / 64.f);
        float d = v - mean;
        float s2 = d * d;
#pragma unroll
        for (int off = 32; off > 0; off >>= 1) s2 += __shfl_xor(s2, off);
        float rstd = rsqrtf(s2 * (1.f / 64.f) + EPSV);
        float o = d * rstd * g + bl;
        xnb[(size_t)row * 64 + lane] = f2bf(o);
    }
}

// ---- bhist: 256-bucket histogram (LDS-aggregated) -----------------------------
__global__ __launch_bounds__(256) void bhist_kernel(
    const int* __restrict__ rowsrc, const int* __restrict__ colsrc,
    int* __restrict__ bcnt)
{
    __shared__ int h[NBKT];
    h[threadIdx.x] = 0;
    __syncthreads();
    for (int i = blockIdx.x * 256 + threadIdx.x; i < EE; i += gridDim.x * 256) {
        atomicAdd(&h[rowsrc[i] >> 11], 1);
        atomicAdd(&h[128 + (colsrc[i] >> 11)], 1);
    }
    __syncthreads();
    int v = h[threadIdx.x];
    if (v) atomicAdd(&bcnt[threadIdx.x], v);
}

// ---- bscan: exclusive scan of 256 bucket counts; seeds wcur, bbase, ptr[NB] ---
__global__ __launch_bounds__(256) void bscan_kernel(
    const int* __restrict__ bcnt, int* __restrict__ bbase,
    int* __restrict__ wcur, int* __restrict__ ptr)
{
    const int t = threadIdx.x;
    __shared__ int sm[256];
    int orig = bcnt[t];
    sm[t] = orig;
    __syncthreads();
    for (int off = 1; off < 256; off <<= 1) {
        int v = (t >= off) ? sm[t - off] : 0;
        __syncthreads();
        sm[t] += v;
        __syncthreads();
    }
    int excl = sm[t] - orig;
    bbase[t] = excl;
    wcur[t]  = excl;
    if (t == 255) { bbase[256] = 2 * EE; ptr[NB] = 2 * EE; }
}

// ---- partA: single-scan 256-way partition into bucket-staged (s,dst,att) ------
__global__ __launch_bounds__(256) void partA_kernel(
    const int* __restrict__ rowsrc, const int* __restrict__ rowdst,
    const float* __restrict__ ratt,
    const int* __restrict__ colsrc, const int* __restrict__ coldst,
    const float* __restrict__ catt,
    int* __restrict__ wcur,
    long long* __restrict__ psd, float* __restrict__ patt)
{
    __shared__ int hcnt[NBKT], hbase[NBKT];
    const int tid = threadIdx.x;

    for (long long t0 = (long long)blockIdx.x * 1024; t0 < 2LL * EE;
         t0 += (long long)gridDim.x * 1024) {
        hcnt[tid] = 0;
        __syncthreads();

        int w[4], rank[4], dstv[4], sfl[4];
        float attv[4];
#pragma unroll
        for (int u = 0; u < 4; ++u) {
            long long i = t0 + u * 256 + tid;
            if (i < 2LL * EE) {
                bool isrow = i < EE;
                long long j = isrow ? i : i - EE;
                int s   = isrow ? __builtin_nontemporal_load(&rowsrc[j])
                                : __builtin_nontemporal_load(&colsrc[j]);
                dstv[u] = isrow ? __builtin_nontemporal_load(&rowdst[j])
                                : __builtin_nontemporal_load(&coldst[j]);
                attv[u] = isrow ? __builtin_nontemporal_load(&ratt[j])
                                : __builtin_nontemporal_load(&catt[j]);
                sfl[u]  = (isrow ? 0 : NN) + s;
                w[u]    = sfl[u] >> 11;           // bucket of 2048 flat-nodes
                rank[u] = atomicAdd(&hcnt[w[u]], 1);
            } else {
                w[u] = -1;
            }
        }
        __syncthreads();
        hbase[tid] = atomicAdd(&wcur[tid], hcnt[tid]);
        __syncthreads();
#pragma unroll
        for (int u = 0; u < 4; ++u) {
            if (w[u] >= 0) {
                int pos = hbase[w[u]] + rank[u];
                psd[pos]  = ((long long)sfl[u] << 32) | (unsigned int)dstv[u];
                patt[pos] = attv[u];
            }
        }
        __syncthreads();   // before hcnt reuse
    }
}

// ---- partB_lds: per-bucket LDS counting sort; writes ptr + sorted edges -------
// 512 threads (8 waves/CU) for memory-latency hiding at 1 block/CU.
// LDS: lcnt 8KB + lrec 142KB + sm 2KB = 152KB.
__global__ __launch_bounds__(512) void partB_lds(
    const int* __restrict__ bbase,
    const long long* __restrict__ psd, const float* __restrict__ patt,
    int* __restrict__ ptr, int2* __restrict__ edges)
{
    __shared__ int lcnt[BKN];          // counts -> (after scan) cursor
    __shared__ long long lrec[CAP];    // sorted records
    __shared__ int sm[512];
    const int tid  = threadIdx.x;
    const int b    = blockIdx.x;
    const int nb0  = b * BKN;
    const int base = bbase[b];
    const int end  = bbase[b + 1];
    const int cnt  = end - base;

    for (int i = tid; i < BKN; i += 512) lcnt[i] = 0;
    __syncthreads();

    // pass1: per-node counts
    for (int i = tid; i < cnt; i += 512) {
        int s = (int)(psd[base + i] >> 32);
        atomicAdd(&lcnt[s - nb0], 1);
    }
    __syncthreads();

    // pass2: block-exclusive scan of 2048 counts (4 per thread);
    // write offsets back into lcnt and global ptr
    int loc[4], tsum = 0;
#pragma unroll
    for (int j = 0; j < 4; ++j) { loc[j] = lcnt[tid * 4 + j]; tsum += loc[j]; }
    sm[tid] = tsum;
    __syncthreads();
    for (int off = 1; off < 512; off <<= 1) {
        int v = (tid >= off) ? sm[tid - off] : 0;
        __syncthreads();
        sm[tid] += v;
        __syncthreads();
    }
    int run = sm[tid] - tsum;
#pragma unroll
    for (int j = 0; j < 4; ++j) {
        lcnt[tid * 4 + j] = run;
        ptr[nb0 + tid * 4 + j] = base + run;
        run += loc[j];
    }
    __syncthreads();

    // pass3: scatter records into LDS (spill path for impossible overflow)
    for (int i = tid; i < cnt; i += 512) {
        long long q = psd[base + i];
        float    a = patt[base + i];
        int s = (int)(q >> 32);
        int d = (int)(q & 0xffffffffLL);
        int off = atomicAdd(&lcnt[s - nb0], 1);
        long long rec = ((long long)__float_as_int(a) << 32) | (unsigned int)d;
        if (off < CAP) lrec[off] = rec;
        else edges[base + off] = make_int2(d, __float_as_int(a));
    }
    __syncthreads();

    // pass4: sequential coalesced write of sorted records
    const int lim = (cnt < CAP) ? cnt : CAP;
    for (int i = tid; i < lim; i += 512) {
        long long rec = lrec[i];
        edges[base + i] = make_int2((int)(rec & 0xffffffffLL), (int)(rec >> 32));
    }
}

// ---- pure gather, 4 concurrent streams per wave (R9-proven version) -----------
__global__ __launch_bounds__(256) void gather_kernel(
    const unsigned short* __restrict__ xnb,
    const int* __restrict__ ptr, const int2* __restrict__ edges,
    unsigned short* __restrict__ rxb, unsigned short* __restrict__ cxb,
    float2* __restrict__ attsum)
{
    const int lane = threadIdx.x & 63;
    const int wid  = (blockIdx.x * 256 + threadIdx.x) >> 6;
    const int nw   = (gridDim.x * 256) >> 6;
    const int HALF = NN / 2;

    for (int n = wid; n < HALF; n += nw) {
        const int m = n + HALF;
        const int i0 = ptr[n],      e0 = ptr[n + 1];
        const int i1 = ptr[NN + n], e1 = ptr[NN + n + 1];
        const int i2 = ptr[m],      e2 = ptr[m + 1];
        const int i3 = ptr[NN + m], e3 = ptr[NN + m + 1];
        const int len0 = e0 - i0, len1 = e1 - i1, len2 = e2 - i2, len3 = e3 - i3;
        int maxlen = max(max(len0, len1), max(len2, len3));

        float rx0 = 0.f, cx0 = 0.f, rx1 = 0.f, cx1 = 0.f;
        float ras0 = 0.f, cas0 = 0.f, ras1 = 0.f, cas1 = 0.f;

#pragma unroll 2
        for (int k = 0; k < maxlen; ++k) {
            int j0 = min(i0 + ((k < len0) ? k : 0), 2 * EE - 1);
            int j1 = min(i1 + ((k < len1) ? k : 0), 2 * EE - 1);
            int j2 = min(i2 + ((k < len2) ? k : 0), 2 * EE - 1);
            int j3 = min(i3 + ((k < len3) ? k : 0), 2 * EE - 1);
            int2 p0 = edges[j0];
            int2 p1 = edges[j1];
            int2 p2 = edges[j2];
            int2 p3 = edges[j3];
            float v0 = bf2f(xnb[(size_t)p0.x * 64 + lane]);
            float v1 = bf2f(xnb[(size_t)p1.x * 64 + lane]);
            float v2 = bf2f(xnb[(size_t)p2.x * 64 + lane]);
            float v3 = bf2f(xnb[(size_t)p3.x * 64 + lane]);
            float a0 = (k < len0) ? __int_as_float(p0.y) : 0.f;
            float a1 = (k < len1) ? __int_as_float(p1.y) : 0.f;
            float a2 = (k < len2) ? __int_as_float(p2.y) : 0.f;
            float a3 = (k < len3) ? __int_as_float(p3.y) : 0.f;
            rx0 = fmaf(v0, a0, rx0); ras0 += a0;
            cx0 = fmaf(v1, a1, cx0); cas0 += a1;
            rx1 = fmaf(v2, a2, rx1); ras1 += a2;
            cx1 = fmaf(v3, a3, cx1); cas1 += a3;
        }

        rxb[(size_t)n * 64 + lane] = f2bf(rx0);
        cxb[(size_t)n * 64 + lane] = f2bf(cx0);
        rxb[(size_t)m * 64 + lane] = f2bf(rx1);
        cxb[(size_t)m * 64 + lane] = f2bf(cx1);
        if (lane == 0) {
            attsum[n] = make_float2(ras0, cas0);
            attsum[m] = make_float2(ras1, cas1);
        }
    }
}

// ---- MFMA epilogue: out = bf16(xnb + rx@Wr + cx@Wc + ras·br + cas·bc) ---------
__global__ __launch_bounds__(256) void gemv_mfma(
    const unsigned short* __restrict__ rxb, const unsigned short* __restrict__ cxb,
    const unsigned short* __restrict__ xnb, const float2* __restrict__ attsum,
    const unsigned short* __restrict__ wb16,
    const float* __restrict__ br, const float* __restrict__ bc,
    unsigned short* __restrict__ out, float* __restrict__ stats)
{
    const int lane = threadIdx.x & 63;
    const int wloc = threadIdx.x >> 6;
    const int wid  = (blockIdx.x * 256 + threadIdx.x) >> 6;
    const int nw   = (gridDim.x * 256) >> 6;
    const int lo   = lane & 15;
    const int hi   = lane >> 4;

    const bf16x8* wb = (const bf16x8*)wb16;
    bf16x8 bfr[2][2][4];
#pragma unroll
    for (int m = 0; m < 2; ++m)
#pragma unroll
        for (int kb = 0; kb < 2; ++kb)
#pragma unroll
            for (int t = 0; t < 4; ++t)
                bfr[m][kb][t] = wb[((m * 2 + kb) * 4 + t) * 64 + lane];

    float brv4[4], bcv4[4];
#pragma unroll
    for (int t = 0; t < 4; ++t) {
        brv4[t] = br[t * 16 + lo];
        bcv4[t] = bc[t * 16 + lo];
    }

    float ss[4] = {0.f, 0.f, 0.f, 0.f}, ss2[4] = {0.f, 0.f, 0.f, 0.f};
    const bf16x8* ra = (const bf16x8*)rxb;
    const bf16x8* ca = (const bf16x8*)cxb;

    for (int tile = wid; tile < NN / 16; tile += nw) {
        const int n0 = tile * 16;
        const int arow = n0 + lo;
        bf16x8 a0 = ra[arow * 8 + hi];
        bf16x8 a1 = ra[arow * 8 + 4 + hi];
        bf16x8 c0 = ca[arow * 8 + hi];
        bf16x8 c1 = ca[arow * 8 + 4 + hi];
        float2 an[4];
#pragma unroll
        for (int r = 0; r < 4; ++r) an[r] = attsum[n0 + hi * 4 + r];

#pragma unroll
        for (int t = 0; t < 4; ++t) {
            f32x4 acc = {0.f, 0.f, 0.f, 0.f};
            acc = __builtin_amdgcn_mfma_f32_16x16x32_bf16(a0, bfr[0][0][t], acc, 0, 0, 0);
            acc = __builtin_amdgcn_mfma_f32_16x16x32_bf16(a1, bfr[0][1][t], acc, 0, 0, 0);
            acc = __builtin_amdgcn_mfma_f32_16x16x32_bf16(c0, bfr[1][0][t], acc, 0, 0, 0);
            acc = __builtin_amdgcn_mfma_f32_16x16x32_bf16(c1, bfr[1][1][t], acc, 0, 0, 0);
            const int col = t * 16 + lo;
#pragma unroll
            for (int r = 0; r < 4; ++r) {
                const int n = n0 + hi * 4 + r;
                float v = acc[r] + bf2f(xnb[(size_t)n * 64 + col])
                        + an[r].x * brv4[t] + an[r].y * bcv4[t];
                out[(size_t)n * 64 + col] = f2bf(v);
                ss[t] += v;
                ss2[t] += v * v;
            }
        }
    }

#pragma unroll
    for (int t = 0; t < 4; ++t) {
        ss[t]  += __shfl_xor(ss[t], 16);  ss[t]  += __shfl_xor(ss[t], 32);
        ss2[t] += __shfl_xor(ss2[t], 16); ss2[t] += __shfl_xor(ss2[t], 32);
    }
    __shared__ float ls[4][64], ls2[4][64];
    if (lo == lane) {
#pragma unroll
        for (int t = 0; t < 4; ++t) {
            ls[wloc][t * 16 + lane]  = ss[t];
            ls2[wloc][t * 16 + lane] = ss2[t];
        }
    }
    __syncthreads();
    if (threadIdx.x < 64) {
        int ch = threadIdx.x;
        atomicAdd(&stats[ch],      ls[0][ch] + ls[1][ch] + ls[2][ch] + ls[3][ch]);
        atomicAdd(&stats[64 + ch], ls2[0][ch] + ls2[1][ch] + ls2[2][ch] + ls2[3][ch]);
    }
}

// ------ fused output: affine+leaky -> logits = h@smW + b -> softmax ------------
__global__ __launch_bounds__(256) void out_kernel(
    const unsigned short* __restrict__ agg, const float* __restrict__ ac,
    const float* __restrict__ smW, const float* __restrict__ smb,
    float* __restrict__ out)
{
    __shared__ float sW[64 * 16];
    for (int i = threadIdx.x; i < 64 * 16; i += 256) sW[i] = smW[i];
    __syncthreads();
    const int j = threadIdx.x & 15;
    const int rloc = threadIdx.x >> 4;
    const float bj = smb[j];
    for (int row = blockIdx.x * 16 + rloc; row < NN; row += gridDim.x * 16) {
        float acc = bj;
#pragma unroll
        for (int k = 0; k < 64; ++k) {
            float v = bf2f(agg[(size_t)row * 64 + k]);
            v = v * ac[k] + ac[64 + k];
            v = (v > 0.f) ? v : 0.01f * v;
            acc = fmaf(v, sW[k * 16 + j], acc);
        }
        float m = acc;
#pragma unroll
        for (int off = 8; off > 0; off >>= 1) m = fmaxf(m, __shfl_xor(m, off));
        float e = expf(acc - m);
        float ssum = e;
#pragma unroll
        for (int off = 8; off > 0; off >>= 1) ssum += __shfl_xor(ssum, off);
        out[(size_t)row * 16 + j] = e / ssum;
    }
}

// ------------------------------------------------------------------------------
extern "C" void kernel_launch(void* const* d_in, const int* in_sizes, int n_in,
                              void* d_out, int out_size, void* d_ws, size_t ws_size,
                              hipStream_t stream)
{
    const float* x        = (const float*)d_in[0];
    const float* row_att  = (const float*)d_in[1];
    const float* col_att  = (const float*)d_in[2];
    const float* prelin_W = (const float*)d_in[3];
    const float* prelin_b = (const float*)d_in[4];
    const float* bn0_g    = (const float*)d_in[5];
    const float* bn0_b    = (const float*)d_in[6];
    const float* ln_g     = (const float*)d_in[7];
    const float* ln_b     = (const float*)d_in[8];
    const float* Wrv      = (const float*)d_in[9];
    const float* brv      = (const float*)d_in[10];
    const float* Wcv      = (const float*)d_in[11];
    const float* bcv      = (const float*)d_in[12];
    const float* bn_g     = (const float*)d_in[13];
    const float* bn_b     = (const float*)d_in[14];
    const float* sm_W     = (const float*)d_in[15];
    const float* sm_b     = (const float*)d_in[16];
    const int*   rowsrc   = (const int*)d_in[17];
    const int*   rowdst   = (const int*)d_in[18];
    const int*   colsrc   = (const int*)d_in[19];
    const int*   coldst   = (const int*)d_in[20];
    float* out = (float*)d_out;

    // ---- workspace layout (~175 MB) ----
    const size_t NH = (size_t)NN * 64;
    char* extra = (char*)d_ws;
    unsigned short* A   = (unsigned short*)extra; extra += NH * sizeof(short);
    unsigned short* xnb = (unsigned short*)extra; extra += NH * sizeof(short);
    unsigned short* rxb = (unsigned short*)extra; extra += NH * sizeof(short);
    unsigned short* cxb = (unsigned short*)extra; extra += NH * sizeof(short);
    float2* attsum = (float2*)extra;              extra += (size_t)NN * sizeof(float2);
    float* stats  = (float*)extra;                extra += 3 * 128 * sizeof(float);
    int*   bcnt   = (int*)extra;                  extra += NBKT * sizeof(int);   // zeroed with stats
    float* ac     = (float*)extra;                extra += 3 * 128 * sizeof(float);
    unsigned short* wbuf  = (unsigned short*)extra; extra += 16384 * sizeof(short);
    unsigned short* wbufS = (unsigned short*)extra; extra += 14336 * sizeof(short);
    int*   bbase  = (int*)extra;                  extra += (NBKT + 1) * sizeof(int);
    int*   wcur   = (int*)extra;                  extra += NBKT * sizeof(int);
    int*   ptr    = (int*)extra;                  extra += (NB + 1) * sizeof(int);
    int2*  edges  = (int2*)extra;                 extra += 2 * (size_t)EE * sizeof(int2);

    // staging aliases rxb/cxb (dead until first gather; CSR build precedes it)
    long long* psd = (long long*)rxb;   // 2EE*8B = 33.5 MB = rxb exactly
    float*    patt = (float*)cxb;       // 2EE*4B = 16.8 MB (first half of cxb)

    // one memset covers stats (384 f32) + bcnt (256 i32), contiguous
    hipMemsetAsync(stats, 0, (3 * 128 + NBKT) * sizeof(float), stream);

    // ---- CSR build (used by both layers) ----
    bhist_kernel<<<1024, 256, 0, stream>>>(rowsrc, colsrc, bcnt);
    bscan_kernel<<<1, 256, 0, stream>>>(bcnt, bbase, wcur, ptr);
    partA_kernel<<<1024, 256, 0, stream>>>(rowsrc, rowdst, row_att,
                                           colsrc, coldst, col_att,
                                           wcur, psd, patt);
    partB_lds<<<NBKT, 512, 0, stream>>>(bbase, psd, patt, ptr, edges);
    w_all<<<120, 256, 0, stream>>>(Wrv, Wcv, prelin_W, wbuf, wbufS);

    // ---- stem (MFMA, stats fused) ----
    stem_mfma<<<NN / 64, 256, 0, stream>>>(x, wbufS, prelin_b, A, stats);
    finalize_bn<<<1, 64, 0, stream>>>(stats, bn0_g, bn0_b, ac);

    // ---- layer 0 ----
    ln_kernel<0><<<4096, 256, 0, stream>>>(A, ac, ln_g, ln_b, xnb);
    gather_kernel<<<8192, 256, 0, stream>>>(xnb, ptr, edges, rxb, cxb, attsum);
    gemv_mfma<<<2048, 256, 0, stream>>>(rxb, cxb, xnb, attsum, wbuf,
                                        brv, bcv, A, stats + 128);
    finalize_bn<<<1, 64, 0, stream>>>(stats + 128, bn_g, bn_b, ac + 128);

    // ---- layer 1 ----
    ln_kernel<1><<<4096, 256, 0, stream>>>(A, ac + 128, ln_g + 64, ln_b + 64, xnb);
    gather_kernel<<<8192, 256, 0, stream>>>(xnb, ptr, edges, rxb, cxb, attsum);
    gemv_mfma<<<2048, 256, 0, stream>>>(rxb, cxb, xnb, attsum, wbuf + 8192,
                                        brv + 64, bcv + 64, A, stats + 256);
    finalize_bn<<<1, 64, 0, stream>>>(stats + 256, bn_g + 64, bn_b + 64, ac + 256);

    // ---- output head ----
    out_kernel<<<2048, 256, 0, stream>>>(A, ac + 256, sm_W, sm_b, out);
}

// Round 21
// 1000.135 us; speedup vs baseline: 1.3964x; 1.0512x over previous
//
#include <hip/hip_runtime.h>
#include <math.h>

#define NN   262144      // nodes
#define CIN  200         // input channels
#define EE   2097152     // edges
#define NB   (2*NN)      // flat count/ptr sections: [row | col]
#define BKN  2048        // flat-nodes per sort bucket
#define NBKT 256         // buckets
#define CAP  18176       // LDS record capacity per bucket (mean 16384, sd 128)
#define EPSV 1e-5f

typedef __bf16 bf16x8 __attribute__((ext_vector_type(8)));
typedef float  f32x4  __attribute__((ext_vector_type(4)));

__device__ __forceinline__ unsigned short f2bf(float f) {
    unsigned int u = __float_as_uint(f);
    unsigned int r = (u + 0x7fffu + ((u >> 16) & 1u)) >> 16;
    return (unsigned short)r;
}
__device__ __forceinline__ float bf2f(unsigned short u) {
    return __uint_as_float(((unsigned int)u) << 16);
}

// ---- combined weight pre-swizzle: layer weights + stem weights ---------------
__global__ __launch_bounds__(256) void w_all(
    const float* __restrict__ Wrv, const float* __restrict__ Wcv,
    const float* __restrict__ Wstem,
    unsigned short* __restrict__ wbuf, unsigned short* __restrict__ wbufS)
{
    int idx = blockIdx.x * 256 + threadIdx.x;
    if (idx < 16384) {
        int e    = idx & 7;
        int lane = (idx >> 3) & 63;
        int t    = (idx >> 9) & 3;
        int kb   = (idx >> 11) & 1;
        int m    = (idx >> 12) & 1;
        int L    = (idx >> 13) & 1;
        const float* W = (m ? Wcv : Wrv) + L * 4096;
        float w = W[(kb * 32 + ((lane >> 4) & 3) * 8 + e) * 64 + t * 16 + (lane & 15)];
        wbuf[idx] = f2bf(w);
    } else if (idx < 16384 + 14336) {
        int j    = idx - 16384;
        int e    = j & 7;
        int lane = (j >> 3) & 63;
        int f    = j >> 9;          // 0..27
        int t    = f & 3;
        int kb   = f >> 2;
        int k    = kb * 32 + ((lane >> 4) & 3) * 8 + e;
        float w  = (k < CIN) ? Wstem[k * 64 + t * 16 + (lane & 15)] : 0.f;
        wbufS[j] = f2bf(w);
    }
}

// ------- stem via MFMA: t = bf16(x @ W + b), fused fp32 BN stats ---------------
__global__ __launch_bounds__(256) void stem_mfma(
    const float* __restrict__ x, const unsigned short* __restrict__ wbS,
    const float* __restrict__ bias, unsigned short* __restrict__ t,
    float* __restrict__ stats)
{
    const int lane = threadIdx.x & 63;
    const int wloc = threadIdx.x >> 6;
    const int lo   = lane & 15;
    const int hi   = lane >> 4;
    const int n0   = blockIdx.x * 64 + wloc * 16;

    float bb4[4];
#pragma unroll
    for (int tt = 0; tt < 4; ++tt) bb4[tt] = bias[tt * 16 + lo];

    f32x4 acc[4];
#pragma unroll
    for (int tt = 0; tt < 4; ++tt) acc[tt] = (f32x4){0.f, 0.f, 0.f, 0.f};

    const bf16x8* wb = (const bf16x8*)wbS;
    const float* xrow = x + (size_t)(n0 + lo) * CIN;

#pragma unroll
    for (int kb = 0; kb < 7; ++kb) {
        union { bf16x8 b; unsigned short u[8]; } A;
        if (kb < 6 || hi == 0) {
            const float* px = xrow + kb * 32 + hi * 8;
            float4 u0 = *(const float4*)px;
            float4 u1 = *(const float4*)(px + 4);
            A.u[0] = f2bf(u0.x); A.u[1] = f2bf(u0.y);
            A.u[2] = f2bf(u0.z); A.u[3] = f2bf(u0.w);
            A.u[4] = f2bf(u1.x); A.u[5] = f2bf(u1.y);
            A.u[6] = f2bf(u1.z); A.u[7] = f2bf(u1.w);
        } else {
#pragma unroll
            for (int i = 0; i < 8; ++i) A.u[i] = 0;
        }
#pragma unroll
        for (int tt = 0; tt < 4; ++tt)
            acc[tt] = __builtin_amdgcn_mfma_f32_16x16x32_bf16(
                A.b, wb[(kb * 4 + tt) * 64 + lane], acc[tt], 0, 0, 0);
    }

    float ss[4] = {0.f, 0.f, 0.f, 0.f}, ss2[4] = {0.f, 0.f, 0.f, 0.f};
#pragma unroll
    for (int tt = 0; tt < 4; ++tt) {
        const int col = tt * 16 + lo;
#pragma unroll
        for (int r = 0; r < 4; ++r) {
            const int n = n0 + hi * 4 + r;
            float v = acc[tt][r] + bb4[tt];
            t[(size_t)n * 64 + col] = f2bf(v);
            ss[tt] += v;
            ss2[tt] += v * v;
        }
    }

#pragma unroll
    for (int tt = 0; tt < 4; ++tt) {
        ss[tt]  += __shfl_xor(ss[tt], 16);  ss[tt]  += __shfl_xor(ss[tt], 32);
        ss2[tt] += __shfl_xor(ss2[tt], 16); ss2[tt] += __shfl_xor(ss2[tt], 32);
    }
    __shared__ float ls[4][64], ls2[4][64];
    if (lo == lane) {
#pragma unroll
        for (int tt = 0; tt < 4; ++tt) {
            ls[wloc][tt * 16 + lane]  = ss[tt];
            ls2[wloc][tt * 16 + lane] = ss2[tt];
        }
    }
    __syncthreads();
    if (threadIdx.x < 64) {
        int ch = threadIdx.x;
        atomicAdd(&stats[ch],      ls[0][ch] + ls[1][ch] + ls[2][ch] + ls[3][ch]);
        atomicAdd(&stats[64 + ch], ls2[0][ch] + ls2[1][ch] + ls2[2][ch] + ls2[3][ch]);
    }
}

// fold BN into per-channel affine:  bn(v) = v*a + c
__global__ void finalize_bn(const float* __restrict__ stats,
                            const float* __restrict__ g, const float* __restrict__ b,
                            float* __restrict__ ac)
{
    int c = threadIdx.x;
    float mean = stats[c] * (1.f / NN);
    float var  = stats[64 + c] * (1.f / NN) - mean * mean;
    float rstd = rsqrtf(var + EPSV);
    float a = g[c] * rstd;
    ac[c]      = a;
    ac[64 + c] = b[c] - mean * a;
}

// ---- ln (vectorized, G13): 16 lanes/row x ushort4; 4 rows per wave/iter -------
template <int RELU>
__global__ __launch_bounds__(256) void ln_kernel(
    const unsigned short* __restrict__ u, const float* __restrict__ ac,
    const float* __restrict__ lng, const float* __restrict__ lnb,
    unsigned short* __restrict__ xnb)
{
    const int lane = threadIdx.x & 63;
    const int sub  = lane >> 4;          // row within wave's group of 4
    const int c4   = (lane & 15) * 4;    // channel base
    const int wid  = (blockIdx.x * 256 + threadIdx.x) >> 6;
    const int nw   = (gridDim.x * 256) >> 6;

    const float4 av = *(const float4*)&ac[c4];
    const float4 bv = *(const float4*)&ac[64 + c4];
    const float4 gv = *(const float4*)&lng[c4];
    const float4 lv = *(const float4*)&lnb[c4];

    for (int r0 = wid * 4; r0 < NN; r0 += nw * 4) {
        const size_t off = (size_t)(r0 + sub) * 64 + c4;
        ushort4 in = *(const ushort4*)&u[off];
        float v0 = bf2f(in.x) * av.x + bv.x;
        float v1 = bf2f(in.y) * av.y + bv.y;
        float v2 = bf2f(in.z) * av.z + bv.z;
        float v3 = bf2f(in.w) * av.w + bv.w;
        if (RELU) {
            v0 = (v0 > 0.f) ? v0 : 0.01f * v0;
            v1 = (v1 > 0.f) ? v1 : 0.01f * v1;
            v2 = (v2 > 0.f) ? v2 : 0.01f * v2;
            v3 = (v3 > 0.f) ? v3 : 0.01f * v3;
        }
        float s = v0 + v1 + v2 + v3;
        s += __shfl_xor(s, 1); s += __shfl_xor(s, 2);
        s += __shfl_xor(s, 4); s += __shfl_xor(s, 8);
        float mean = s * (1.f / 64.f);
        float d0 = v0 - mean, d1 = v1 - mean, d2 = v2 - mean, d3 = v3 - mean;
        float s2 = d0 * d0 + d1 * d1 + d2 * d2 + d3 * d3;
        s2 += __shfl_xor(s2, 1); s2 += __shfl_xor(s2, 2);
        s2 += __shfl_xor(s2, 4); s2 += __shfl_xor(s2, 8);
        float rstd = rsqrtf(s2 * (1.f / 64.f) + EPSV);
        ushort4 o;
        o.x = f2bf(d0 * rstd * gv.x + lv.x);
        o.y = f2bf(d1 * rstd * gv.y + lv.y);
        o.z = f2bf(d2 * rstd * gv.z + lv.z);
        o.w = f2bf(d3 * rstd * gv.w + lv.w);
        *(ushort4*)&xnb[off] = o;
    }
}

// ---- bhist: 256-bucket histogram (LDS-aggregated) -----------------------------
__global__ __launch_bounds__(256) void bhist_kernel(
    const int* __restrict__ rowsrc, const int* __restrict__ colsrc,
    int* __restrict__ bcnt)
{
    __shared__ int h[NBKT];
    h[threadIdx.x] = 0;
    __syncthreads();
    for (int i = blockIdx.x * 256 + threadIdx.x; i < EE; i += gridDim.x * 256) {
        atomicAdd(&h[rowsrc[i] >> 11], 1);
        atomicAdd(&h[128 + (colsrc[i] >> 11)], 1);
    }
    __syncthreads();
    int v = h[threadIdx.x];
    if (v) atomicAdd(&bcnt[threadIdx.x], v);
}

// ---- bscan: exclusive scan of 256 bucket counts; seeds wcur, bbase, ptr[NB] ---
__global__ __launch_bounds__(256) void bscan_kernel(
    const int* __restrict__ bcnt, int* __restrict__ bbase,
    int* __restrict__ wcur, int* __restrict__ ptr)
{
    const int t = threadIdx.x;
    __shared__ int sm[256];
    int orig = bcnt[t];
    sm[t] = orig;
    __syncthreads();
    for (int off = 1; off < 256; off <<= 1) {
        int v = (t >= off) ? sm[t - off] : 0;
        __syncthreads();
        sm[t] += v;
        __syncthreads();
    }
    int excl = sm[t] - orig;
    bbase[t] = excl;
    wcur[t]  = excl;
    if (t == 255) { bbase[256] = 2 * EE; ptr[NB] = 2 * EE; }
}

// ---- partA: single-scan 256-way partition into bucket-staged (s,dst,att) ------
__global__ __launch_bounds__(256) void partA_kernel(
    const int* __restrict__ rowsrc, const int* __restrict__ rowdst,
    const float* __restrict__ ratt,
    const int* __restrict__ colsrc, const int* __restrict__ coldst,
    const float* __restrict__ catt,
    int* __restrict__ wcur,
    long long* __restrict__ psd, float* __restrict__ patt)
{
    __shared__ int hcnt[NBKT], hbase[NBKT];
    const int tid = threadIdx.x;

    for (long long t0 = (long long)blockIdx.x * 1024; t0 < 2LL * EE;
         t0 += (long long)gridDim.x * 1024) {
        hcnt[tid] = 0;
        __syncthreads();

        int w[4], rank[4], dstv[4], sfl[4];
        float attv[4];
#pragma unroll
        for (int u = 0; u < 4; ++u) {
            long long i = t0 + u * 256 + tid;
            if (i < 2LL * EE) {
                bool isrow = i < EE;
                long long j = isrow ? i : i - EE;
                int s   = isrow ? __builtin_nontemporal_load(&rowsrc[j])
                                : __builtin_nontemporal_load(&colsrc[j]);
                dstv[u] = isrow ? __builtin_nontemporal_load(&rowdst[j])
                                : __builtin_nontemporal_load(&coldst[j]);
                attv[u] = isrow ? __builtin_nontemporal_load(&ratt[j])
                                : __builtin_nontemporal_load(&catt[j]);
                sfl[u]  = (isrow ? 0 : NN) + s;
                w[u]    = sfl[u] >> 11;           // bucket of 2048 flat-nodes
                rank[u] = atomicAdd(&hcnt[w[u]], 1);
            } else {
                w[u] = -1;
            }
        }
        __syncthreads();
        hbase[tid] = atomicAdd(&wcur[tid], hcnt[tid]);
        __syncthreads();
#pragma unroll
        for (int u = 0; u < 4; ++u) {
            if (w[u] >= 0) {
                int pos = hbase[w[u]] + rank[u];
                psd[pos]  = ((long long)sfl[u] << 32) | (unsigned int)dstv[u];
                patt[pos] = attv[u];
            }
        }
        __syncthreads();   // before hcnt reuse
    }
}

// ---- partB_lds: per-bucket LDS counting sort; writes ptr + sorted edges -------
__global__ __launch_bounds__(512) void partB_lds(
    const int* __restrict__ bbase,
    const long long* __restrict__ psd, const float* __restrict__ patt,
    int* __restrict__ ptr, int2* __restrict__ edges)
{
    __shared__ int lcnt[BKN];          // counts -> (after scan) cursor
    __shared__ long long lrec[CAP];    // sorted records
    __shared__ int sm[512];
    const int tid  = threadIdx.x;
    const int b    = blockIdx.x;
    const int nb0  = b * BKN;
    const int base = bbase[b];
    const int end  = bbase[b + 1];
    const int cnt  = end - base;

    for (int i = tid; i < BKN; i += 512) lcnt[i] = 0;
    __syncthreads();

    // pass1: per-node counts
    for (int i = tid; i < cnt; i += 512) {
        int s = (int)(psd[base + i] >> 32);
        atomicAdd(&lcnt[s - nb0], 1);
    }
    __syncthreads();

    // pass2: block-exclusive scan of 2048 counts (4 per thread);
    // write offsets back into lcnt and global ptr
    int loc[4], tsum = 0;
#pragma unroll
    for (int j = 0; j < 4; ++j) { loc[j] = lcnt[tid * 4 + j]; tsum += loc[j]; }
    sm[tid] = tsum;
    __syncthreads();
    for (int off = 1; off < 512; off <<= 1) {
        int v = (tid >= off) ? sm[tid - off] : 0;
        __syncthreads();
        sm[tid] += v;
        __syncthreads();
    }
    int run = sm[tid] - tsum;
#pragma unroll
    for (int j = 0; j < 4; ++j) {
        lcnt[tid * 4 + j] = run;
        ptr[nb0 + tid * 4 + j] = base + run;
        run += loc[j];
    }
    __syncthreads();

    // pass3: scatter records into LDS (spill path for impossible overflow)
    for (int i = tid; i < cnt; i += 512) {
        long long q = psd[base + i];
        float    a = patt[base + i];
        int s = (int)(q >> 32);
        int d = (int)(q & 0xffffffffLL);
        int off = atomicAdd(&lcnt[s - nb0], 1);
        long long rec = ((long long)__float_as_int(a) << 32) | (unsigned int)d;
        if (off < CAP) lrec[off] = rec;
        else edges[base + off] = make_int2(d, __float_as_int(a));
    }
    __syncthreads();

    // pass4: sequential coalesced write of sorted records
    const int lim = (cnt < CAP) ? cnt : CAP;
    for (int i = tid; i < lim; i += 512) {
        long long rec = lrec[i];
        edges[base + i] = make_int2((int)(rec & 0xffffffffLL), (int)(rec >> 32));
    }
}

// ---- pure gather, 4 concurrent streams per wave, deeper unroll ---------------
__global__ __launch_bounds__(256) void gather_kernel(
    const unsigned short* __restrict__ xnb,
    const int* __restrict__ ptr, const int2* __restrict__ edges,
    unsigned short* __restrict__ rxb, unsigned short* __restrict__ cxb,
    float2* __restrict__ attsum)
{
    const int lane = threadIdx.x & 63;
    const int wid  = (blockIdx.x * 256 + threadIdx.x) >> 6;
    const int nw   = (gridDim.x * 256) >> 6;
    const int HALF = NN / 2;

    for (int n = wid; n < HALF; n += nw) {
        const int m = n + HALF;
        const int i0 = ptr[n],      e0 = ptr[n + 1];
        const int i1 = ptr[NN + n], e1 = ptr[NN + n + 1];
        const int i2 = ptr[m],      e2 = ptr[m + 1];
        const int i3 = ptr[NN + m], e3 = ptr[NN + m + 1];
        const int len0 = e0 - i0, len1 = e1 - i1, len2 = e2 - i2, len3 = e3 - i3;
        int maxlen = max(max(len0, len1), max(len2, len3));

        float rx0 = 0.f, cx0 = 0.f, rx1 = 0.f, cx1 = 0.f;
        float ras0 = 0.f, cas0 = 0.f, ras1 = 0.f, cas1 = 0.f;

#pragma unroll 4
        for (int k = 0; k < maxlen; ++k) {
            int j0 = min(i0 + ((k < len0) ? k : 0), 2 * EE - 1);
            int j1 = min(i1 + ((k < len1) ? k : 0), 2 * EE - 1);
            int j2 = min(i2 + ((k < len2) ? k : 0), 2 * EE - 1);
            int j3 = min(i3 + ((k < len3) ? k : 0), 2 * EE - 1);
            int2 p0 = edges[j0];
            int2 p1 = edges[j1];
            int2 p2 = edges[j2];
            int2 p3 = edges[j3];
            float v0 = bf2f(xnb[(size_t)p0.x * 64 + lane]);
            float v1 = bf2f(xnb[(size_t)p1.x * 64 + lane]);
            float v2 = bf2f(xnb[(size_t)p2.x * 64 + lane]);
            float v3 = bf2f(xnb[(size_t)p3.x * 64 + lane]);
            float a0 = (k < len0) ? __int_as_float(p0.y) : 0.f;
            float a1 = (k < len1) ? __int_as_float(p1.y) : 0.f;
            float a2 = (k < len2) ? __int_as_float(p2.y) : 0.f;
            float a3 = (k < len3) ? __int_as_float(p3.y) : 0.f;
            rx0 = fmaf(v0, a0, rx0); ras0 += a0;
            cx0 = fmaf(v1, a1, cx0); cas0 += a1;
            rx1 = fmaf(v2, a2, rx1); ras1 += a2;
            cx1 = fmaf(v3, a3, cx1); cas1 += a3;
        }

        rxb[(size_t)n * 64 + lane] = f2bf(rx0);
        cxb[(size_t)n * 64 + lane] = f2bf(cx0);
        rxb[(size_t)m * 64 + lane] = f2bf(rx1);
        cxb[(size_t)m * 64 + lane] = f2bf(cx1);
        if (lane == 0) {
            attsum[n] = make_float2(ras0, cas0);
            attsum[m] = make_float2(ras1, cas1);
        }
    }
}

// ---- MFMA epilogue: out = bf16(xnb + rx@Wr + cx@Wc + ras·br + cas·bc) ---------
__global__ __launch_bounds__(256) void gemv_mfma(
    const unsigned short* __restrict__ rxb, const unsigned short* __restrict__ cxb,
    const unsigned short* __restrict__ xnb, const float2* __restrict__ attsum,
    const unsigned short* __restrict__ wb16,
    const float* __restrict__ br, const float* __restrict__ bc,
    unsigned short* __restrict__ out, float* __restrict__ stats)
{
    const int lane = threadIdx.x & 63;
    const int wloc = threadIdx.x >> 6;
    const int wid  = (blockIdx.x * 256 + threadIdx.x) >> 6;
    const int nw   = (gridDim.x * 256) >> 6;
    const int lo   = lane & 15;
    const int hi   = lane >> 4;

    const bf16x8* wb = (const bf16x8*)wb16;
    bf16x8 bfr[2][2][4];
#pragma unroll
    for (int m = 0; m < 2; ++m)
#pragma unroll
        for (int kb = 0; kb < 2; ++kb)
#pragma unroll
            for (int t = 0; t < 4; ++t)
                bfr[m][kb][t] = wb[((m * 2 + kb) * 4 + t) * 64 + lane];

    float brv4[4], bcv4[4];
#pragma unroll
    for (int t = 0; t < 4; ++t) {
        brv4[t] = br[t * 16 + lo];
        bcv4[t] = bc[t * 16 + lo];
    }

    float ss[4] = {0.f, 0.f, 0.f, 0.f}, ss2[4] = {0.f, 0.f, 0.f, 0.f};
    const bf16x8* ra = (const bf16x8*)rxb;
    const bf16x8* ca = (const bf16x8*)cxb;

    for (int tile = wid; tile < NN / 16; tile += nw) {
        const int n0 = tile * 16;
        const int arow = n0 + lo;
        bf16x8 a0 = ra[arow * 8 + hi];
        bf16x8 a1 = ra[arow * 8 + 4 + hi];
        bf16x8 c0 = ca[arow * 8 + hi];
        bf16x8 c1 = ca[arow * 8 + 4 + hi];
        float2 an[4];
#pragma unroll
        for (int r = 0; r < 4; ++r) an[r] = attsum[n0 + hi * 4 + r];

#pragma unroll
        for (int t = 0; t < 4; ++t) {
            f32x4 acc = {0.f, 0.f, 0.f, 0.f};
            acc = __builtin_amdgcn_mfma_f32_16x16x32_bf16(a0, bfr[0][0][t], acc, 0, 0, 0);
            acc = __builtin_amdgcn_mfma_f32_16x16x32_bf16(a1, bfr[0][1][t], acc, 0, 0, 0);
            acc = __builtin_amdgcn_mfma_f32_16x16x32_bf16(c0, bfr[1][0][t], acc, 0, 0, 0);
            acc = __builtin_amdgcn_mfma_f32_16x16x32_bf16(c1, bfr[1][1][t], acc, 0, 0, 0);
            const int col = t * 16 + lo;
#pragma unroll
            for (int r = 0; r < 4; ++r) {
                const int n = n0 + hi * 4 + r;
                float v = acc[r] + bf2f(xnb[(size_t)n * 64 + col])
                        + an[r].x * brv4[t] + an[r].y * bcv4[t];
                out[(size_t)n * 64 + col] = f2bf(v);
                ss[t] += v;
                ss2[t] += v * v;
            }
        }
    }

#pragma unroll
    for (int t = 0; t < 4; ++t) {
        ss[t]  += __shfl_xor(ss[t], 16);  ss[t]  += __shfl_xor(ss[t], 32);
        ss2[t] += __shfl_xor(ss2[t], 16); ss2[t] += __shfl_xor(ss2[t], 32);
    }
    __shared__ float ls[4][64], ls2[4][64];
    if (lo == lane) {
#pragma unroll
        for (int t = 0; t < 4; ++t) {
            ls[wloc][t * 16 + lane]  = ss[t];
            ls2[wloc][t * 16 + lane] = ss2[t];
        }
    }
    __syncthreads();
    if (threadIdx.x < 64) {
        int ch = threadIdx.x;
        atomicAdd(&stats[ch],      ls[0][ch] + ls[1][ch] + ls[2][ch] + ls[3][ch]);
        atomicAdd(&stats[64 + ch], ls2[0][ch] + ls2[1][ch] + ls2[2][ch] + ls2[3][ch]);
    }
}

// ------ fused output: affine+leaky -> logits = h@smW + b -> softmax ------------
__global__ __launch_bounds__(256) void out_kernel(
    const unsigned short* __restrict__ agg, const float* __restrict__ ac,
    const float* __restrict__ smW, const float* __restrict__ smb,
    float* __restrict__ out)
{
    __shared__ float sW[64 * 16];
    for (int i = threadIdx.x; i < 64 * 16; i += 256) sW[i] = smW[i];
    __syncthreads();
    const int j = threadIdx.x & 15;
    const int rloc = threadIdx.x >> 4;
    const float bj = smb[j];
    for (int row = blockIdx.x * 16 + rloc; row < NN; row += gridDim.x * 16) {
        float acc = bj;
#pragma unroll
        for (int k = 0; k < 64; ++k) {
            float v = bf2f(agg[(size_t)row * 64 + k]);
            v = v * ac[k] + ac[64 + k];
            v = (v > 0.f) ? v : 0.01f * v;
            acc = fmaf(v, sW[k * 16 + j], acc);
        }
        float m = acc;
#pragma unroll
        for (int off = 8; off > 0; off >>= 1) m = fmaxf(m, __shfl_xor(m, off));
        float e = expf(acc - m);
        float ssum = e;
#pragma unroll
        for (int off = 8; off > 0; off >>= 1) ssum += __shfl_xor(ssum, off);
        out[(size_t)row * 16 + j] = e / ssum;
    }
}

// ------------------------------------------------------------------------------
extern "C" void kernel_launch(void* const* d_in, const int* in_sizes, int n_in,
                              void* d_out, int out_size, void* d_ws, size_t ws_size,
                              hipStream_t stream)
{
    const float* x        = (const float*)d_in[0];
    const float* row_att  = (const float*)d_in[1];
    const float* col_att  = (const float*)d_in[2];
    const float* prelin_W = (const float*)d_in[3];
    const float* prelin_b = (const float*)d_in[4];
    const float* bn0_g    = (const float*)d_in[5];
    const float* bn0_b    = (const float*)d_in[6];
    const float* ln_g     = (const float*)d_in[7];
    const float* ln_b     = (const float*)d_in[8];
    const float* Wrv      = (const float*)d_in[9];
    const float* brv      = (const float*)d_in[10];
    const float* Wcv      = (const float*)d_in[11];
    const float* bcv      = (const float*)d_in[12];
    const float* bn_g     = (const float*)d_in[13];
    const float* bn_b     = (const float*)d_in[14];
    const float* sm_W     = (const float*)d_in[15];
    const float* sm_b     = (const float*)d_in[16];
    const int*   rowsrc   = (const int*)d_in[17];
    const int*   rowdst   = (const int*)d_in[18];
    const int*   colsrc   = (const int*)d_in[19];
    const int*   coldst   = (const int*)d_in[20];
    float* out = (float*)d_out;

    // ---- workspace layout (~175 MB) ----
    const size_t NH = (size_t)NN * 64;
    char* extra = (char*)d_ws;
    unsigned short* A   = (unsigned short*)extra; extra += NH * sizeof(short);
    unsigned short* xnb = (unsigned short*)extra; extra += NH * sizeof(short);
    unsigned short* rxb = (unsigned short*)extra; extra += NH * sizeof(short);
    unsigned short* cxb = (unsigned short*)extra; extra += NH * sizeof(short);
    float2* attsum = (float2*)extra;              extra += (size_t)NN * sizeof(float2);
    float* stats  = (float*)extra;                extra += 3 * 128 * sizeof(float);
    int*   bcnt   = (int*)extra;                  extra += NBKT * sizeof(int);   // zeroed with stats
    float* ac     = (float*)extra;                extra += 3 * 128 * sizeof(float);
    unsigned short* wbuf  = (unsigned short*)extra; extra += 16384 * sizeof(short);
    unsigned short* wbufS = (unsigned short*)extra; extra += 14336 * sizeof(short);
    int*   bbase  = (int*)extra;                  extra += (NBKT + 1) * sizeof(int);
    int*   wcur   = (int*)extra;                  extra += NBKT * sizeof(int);
    int*   ptr    = (int*)extra;                  extra += (NB + 1) * sizeof(int);
    int2*  edges  = (int2*)extra;                 extra += 2 * (size_t)EE * sizeof(int2);

    // staging aliases rxb/cxb (dead until first gather; CSR build precedes it)
    long long* psd = (long long*)rxb;   // 2EE*8B = 33.5 MB = rxb exactly
    float*    patt = (float*)cxb;       // 2EE*4B = 16.8 MB (first half of cxb)

    // one memset covers stats (384 f32) + bcnt (256 i32), contiguous
    hipMemsetAsync(stats, 0, (3 * 128 + NBKT) * sizeof(float), stream);

    // ---- CSR build (used by both layers) ----
    bhist_kernel<<<1024, 256, 0, stream>>>(rowsrc, colsrc, bcnt);
    bscan_kernel<<<1, 256, 0, stream>>>(bcnt, bbase, wcur, ptr);
    partA_kernel<<<1024, 256, 0, stream>>>(rowsrc, rowdst, row_att,
                                           colsrc, coldst, col_att,
                                           wcur, psd, patt);
    partB_lds<<<NBKT, 512, 0, stream>>>(bbase, psd, patt, ptr, edges);
    w_all<<<120, 256, 0, stream>>>(Wrv, Wcv, prelin_W, wbuf, wbufS);

    // ---- stem (MFMA, stats fused) ----
    stem_mfma<<<NN / 64, 256, 0, stream>>>(x, wbufS, prelin_b, A, stats);
    finalize_bn<<<1, 64, 0, stream>>>(stats, bn0_g, bn0_b, ac);

    // ---- layer 0 ----
    ln_kernel<0><<<4096, 256, 0, stream>>>(A, ac, ln_g, ln_b, xnb);
    gather_kernel<<<8192, 256, 0, stream>>>(xnb, ptr, edges, rxb, cxb, attsum);
    gemv_mfma<<<2048, 256, 0, stream>>>(rxb, cxb, xnb, attsum, wbuf,
                                        brv, bcv, A, stats + 128);
    finalize_bn<<<1, 64, 0, stream>>>(stats + 128, bn_g, bn_b, ac + 128);

    // ---- layer 1 ----
    ln_kernel<1><<<4096, 256, 0, stream>>>(A, ac + 128, ln_g + 64, ln_b + 64, xnb);
    gather_kernel<<<8192, 256, 0, stream>>>(xnb, ptr, edges, rxb, cxb, attsum);
    gemv_mfma<<<2048, 256, 0, stream>>>(rxb, cxb, xnb, attsum, wbuf + 8192,
                                        brv + 64, bcv + 64, A, stats + 256);
    finalize_bn<<<1, 64, 0, stream>>>(stats + 256, bn_g + 64, bn_b + 64, ac + 256);

    // ---- output head ----
    out_kernel<<<2048, 256, 0, stream>>>(A, ac + 256, sm_W, sm_b, out);
}

// Round 22
// 995.083 us; speedup vs baseline: 1.4035x; 1.0051x over previous
//
#include <hip/hip_runtime.h>
#include <math.h>

#define NN   262144      // nodes
#define CIN  200         // input channels
#define EE   2097152     // edges
#define NB   (2*NN)      // flat count/ptr sections: [row | col]
#define BKN  2048        // flat-nodes per sort bucket
#define NBKT 256         // buckets
#define CAP  18176       // LDS record capacity per bucket (mean 16384, sd 128)
#define EPSV 1e-5f

typedef __bf16 bf16x8 __attribute__((ext_vector_type(8)));
typedef float  f32x4  __attribute__((ext_vector_type(4)));

__device__ __forceinline__ unsigned short f2bf(float f) {
    unsigned int u = __float_as_uint(f);
    unsigned int r = (u + 0x7fffu + ((u >> 16) & 1u)) >> 16;
    return (unsigned short)r;
}
__device__ __forceinline__ float bf2f(unsigned short u) {
    return __uint_as_float(((unsigned int)u) << 16);
}

// ---- prep: 256-bucket histogram (blocks 0..1023) + weight swizzle (1024..) ----
__global__ __launch_bounds__(256) void prep_kernel(
    const int* __restrict__ rowsrc, const int* __restrict__ colsrc,
    int* __restrict__ bcnt,
    const float* __restrict__ Wrv, const float* __restrict__ Wcv,
    const float* __restrict__ Wstem,
    unsigned short* __restrict__ wbuf, unsigned short* __restrict__ wbufS)
{
    if (blockIdx.x < 1024) {
        __shared__ int h[NBKT];
        h[threadIdx.x] = 0;
        __syncthreads();
        for (int i = blockIdx.x * 256 + threadIdx.x; i < EE; i += 1024 * 256) {
            atomicAdd(&h[rowsrc[i] >> 11], 1);
            atomicAdd(&h[128 + (colsrc[i] >> 11)], 1);
        }
        __syncthreads();
        int v = h[threadIdx.x];
        if (v) atomicAdd(&bcnt[threadIdx.x], v);
    } else {
        int idx = (blockIdx.x - 1024) * 256 + threadIdx.x;
        if (idx < 16384) {
            int e    = idx & 7;
            int lane = (idx >> 3) & 63;
            int t    = (idx >> 9) & 3;
            int kb   = (idx >> 11) & 1;
            int m    = (idx >> 12) & 1;
            int L    = (idx >> 13) & 1;
            const float* W = (m ? Wcv : Wrv) + L * 4096;
            float w = W[(kb * 32 + ((lane >> 4) & 3) * 8 + e) * 64 + t * 16 + (lane & 15)];
            wbuf[idx] = f2bf(w);
        } else if (idx < 16384 + 14336) {
            int j    = idx - 16384;
            int e    = j & 7;
            int lane = (j >> 3) & 63;
            int f    = j >> 9;          // 0..27
            int t    = f & 3;
            int kb   = f >> 2;
            int k    = kb * 32 + ((lane >> 4) & 3) * 8 + e;
            float w  = (k < CIN) ? Wstem[k * 64 + t * 16 + (lane & 15)] : 0.f;
            wbufS[j] = f2bf(w);
        }
    }
}

// ------- stem via MFMA: t = bf16(x @ W + b), fused fp32 BN stats ---------------
__global__ __launch_bounds__(256) void stem_mfma(
    const float* __restrict__ x, const unsigned short* __restrict__ wbS,
    const float* __restrict__ bias, unsigned short* __restrict__ t,
    float* __restrict__ stats)
{
    const int lane = threadIdx.x & 63;
    const int wloc = threadIdx.x >> 6;
    const int lo   = lane & 15;
    const int hi   = lane >> 4;
    const int n0   = blockIdx.x * 64 + wloc * 16;

    float bb4[4];
#pragma unroll
    for (int tt = 0; tt < 4; ++tt) bb4[tt] = bias[tt * 16 + lo];

    f32x4 acc[4];
#pragma unroll
    for (int tt = 0; tt < 4; ++tt) acc[tt] = (f32x4){0.f, 0.f, 0.f, 0.f};

    const bf16x8* wb = (const bf16x8*)wbS;
    const float* xrow = x + (size_t)(n0 + lo) * CIN;

#pragma unroll
    for (int kb = 0; kb < 7; ++kb) {
        union { bf16x8 b; unsigned short u[8]; } A;
        if (kb < 6 || hi == 0) {
            const float* px = xrow + kb * 32 + hi * 8;
            float4 u0 = *(const float4*)px;
            float4 u1 = *(const float4*)(px + 4);
            A.u[0] = f2bf(u0.x); A.u[1] = f2bf(u0.y);
            A.u[2] = f2bf(u0.z); A.u[3] = f2bf(u0.w);
            A.u[4] = f2bf(u1.x); A.u[5] = f2bf(u1.y);
            A.u[6] = f2bf(u1.z); A.u[7] = f2bf(u1.w);
        } else {
#pragma unroll
            for (int i = 0; i < 8; ++i) A.u[i] = 0;
        }
#pragma unroll
        for (int tt = 0; tt < 4; ++tt)
            acc[tt] = __builtin_amdgcn_mfma_f32_16x16x32_bf16(
                A.b, wb[(kb * 4 + tt) * 64 + lane], acc[tt], 0, 0, 0);
    }

    float ss[4] = {0.f, 0.f, 0.f, 0.f}, ss2[4] = {0.f, 0.f, 0.f, 0.f};
#pragma unroll
    for (int tt = 0; tt < 4; ++tt) {
        const int col = tt * 16 + lo;
#pragma unroll
        for (int r = 0; r < 4; ++r) {
            const int n = n0 + hi * 4 + r;
            float v = acc[tt][r] + bb4[tt];
            t[(size_t)n * 64 + col] = f2bf(v);
            ss[tt] += v;
            ss2[tt] += v * v;
        }
    }

#pragma unroll
    for (int tt = 0; tt < 4; ++tt) {
        ss[tt]  += __shfl_xor(ss[tt], 16);  ss[tt]  += __shfl_xor(ss[tt], 32);
        ss2[tt] += __shfl_xor(ss2[tt], 16); ss2[tt] += __shfl_xor(ss2[tt], 32);
    }
    __shared__ float ls[4][64], ls2[4][64];
    if (lo == lane) {
#pragma unroll
        for (int tt = 0; tt < 4; ++tt) {
            ls[wloc][tt * 16 + lane]  = ss[tt];
            ls2[wloc][tt * 16 + lane] = ss2[tt];
        }
    }
    __syncthreads();
    if (threadIdx.x < 64) {
        int ch = threadIdx.x;
        atomicAdd(&stats[ch],      ls[0][ch] + ls[1][ch] + ls[2][ch] + ls[3][ch]);
        atomicAdd(&stats[64 + ch], ls2[0][ch] + ls2[1][ch] + ls2[2][ch] + ls2[3][ch]);
    }
}

// ---- ln (vectorized, BN-affine folded in from raw stats) ----------------------
template <int RELU>
__global__ __launch_bounds__(256) void ln_kernel(
    const unsigned short* __restrict__ u, const float* __restrict__ stats,
    const float* __restrict__ bng, const float* __restrict__ bnb,
    const float* __restrict__ lng, const float* __restrict__ lnb,
    unsigned short* __restrict__ xnb)
{
    const int lane = threadIdx.x & 63;
    const int sub  = lane >> 4;          // row within wave's group of 4
    const int c4   = (lane & 15) * 4;    // channel base
    const int wid  = (blockIdx.x * 256 + threadIdx.x) >> 6;
    const int nw   = (gridDim.x * 256) >> 6;

    // derive BN affine for this thread's 4 channels from raw stats
    float a0, a1, a2, a3, b0, b1, b2, b3;
    {
        float m0 = stats[c4 + 0] * (1.f / NN), q0 = stats[64 + c4 + 0] * (1.f / NN);
        float m1 = stats[c4 + 1] * (1.f / NN), q1 = stats[64 + c4 + 1] * (1.f / NN);
        float m2 = stats[c4 + 2] * (1.f / NN), q2 = stats[64 + c4 + 2] * (1.f / NN);
        float m3 = stats[c4 + 3] * (1.f / NN), q3 = stats[64 + c4 + 3] * (1.f / NN);
        a0 = bng[c4 + 0] * rsqrtf(q0 - m0 * m0 + EPSV); b0 = bnb[c4 + 0] - m0 * a0;
        a1 = bng[c4 + 1] * rsqrtf(q1 - m1 * m1 + EPSV); b1 = bnb[c4 + 1] - m1 * a1;
        a2 = bng[c4 + 2] * rsqrtf(q2 - m2 * m2 + EPSV); b2 = bnb[c4 + 2] - m2 * a2;
        a3 = bng[c4 + 3] * rsqrtf(q3 - m3 * m3 + EPSV); b3 = bnb[c4 + 3] - m3 * a3;
    }
    const float4 gv = *(const float4*)&lng[c4];
    const float4 lv = *(const float4*)&lnb[c4];

    for (int r0 = wid * 4; r0 < NN; r0 += nw * 4) {
        const size_t off = (size_t)(r0 + sub) * 64 + c4;
        ushort4 in = *(const ushort4*)&u[off];
        float v0 = bf2f(in.x) * a0 + b0;
        float v1 = bf2f(in.y) * a1 + b1;
        float v2 = bf2f(in.z) * a2 + b2;
        float v3 = bf2f(in.w) * a3 + b3;
        if (RELU) {
            v0 = (v0 > 0.f) ? v0 : 0.01f * v0;
            v1 = (v1 > 0.f) ? v1 : 0.01f * v1;
            v2 = (v2 > 0.f) ? v2 : 0.01f * v2;
            v3 = (v3 > 0.f) ? v3 : 0.01f * v3;
        }
        float s = v0 + v1 + v2 + v3;
        s += __shfl_xor(s, 1); s += __shfl_xor(s, 2);
        s += __shfl_xor(s, 4); s += __shfl_xor(s, 8);
        float mean = s * (1.f / 64.f);
        float d0 = v0 - mean, d1 = v1 - mean, d2 = v2 - mean, d3 = v3 - mean;
        float s2 = d0 * d0 + d1 * d1 + d2 * d2 + d3 * d3;
        s2 += __shfl_xor(s2, 1); s2 += __shfl_xor(s2, 2);
        s2 += __shfl_xor(s2, 4); s2 += __shfl_xor(s2, 8);
        float rstd = rsqrtf(s2 * (1.f / 64.f) + EPSV);
        ushort4 o;
        o.x = f2bf(d0 * rstd * gv.x + lv.x);
        o.y = f2bf(d1 * rstd * gv.y + lv.y);
        o.z = f2bf(d2 * rstd * gv.z + lv.z);
        o.w = f2bf(d3 * rstd * gv.w + lv.w);
        *(ushort4*)&xnb[off] = o;
    }
}

// ---- bscan: exclusive scan of 256 bucket counts; seeds wcur, bbase, ptr[NB] ---
__global__ __launch_bounds__(256) void bscan_kernel(
    const int* __restrict__ bcnt, int* __restrict__ bbase,
    int* __restrict__ wcur, int* __restrict__ ptr)
{
    const int t = threadIdx.x;
    __shared__ int sm[256];
    int orig = bcnt[t];
    sm[t] = orig;
    __syncthreads();
    for (int off = 1; off < 256; off <<= 1) {
        int v = (t >= off) ? sm[t - off] : 0;
        __syncthreads();
        sm[t] += v;
        __syncthreads();
    }
    int excl = sm[t] - orig;
    bbase[t] = excl;
    wcur[t]  = excl;
    if (t == 255) { bbase[256] = 2 * EE; ptr[NB] = 2 * EE; }
}

// ---- partA: single-scan 256-way partition into bucket-staged (s,dst,att) ------
__global__ __launch_bounds__(256) void partA_kernel(
    const int* __restrict__ rowsrc, const int* __restrict__ rowdst,
    const float* __restrict__ ratt,
    const int* __restrict__ colsrc, const int* __restrict__ coldst,
    const float* __restrict__ catt,
    int* __restrict__ wcur,
    long long* __restrict__ psd, float* __restrict__ patt)
{
    __shared__ int hcnt[NBKT], hbase[NBKT];
    const int tid = threadIdx.x;

    for (long long t0 = (long long)blockIdx.x * 1024; t0 < 2LL * EE;
         t0 += (long long)gridDim.x * 1024) {
        hcnt[tid] = 0;
        __syncthreads();

        int w[4], rank[4], dstv[4], sfl[4];
        float attv[4];
#pragma unroll
        for (int u = 0; u < 4; ++u) {
            long long i = t0 + u * 256 + tid;
            if (i < 2LL * EE) {
                bool isrow = i < EE;
                long long j = isrow ? i : i - EE;
                int s   = isrow ? __builtin_nontemporal_load(&rowsrc[j])
                                : __builtin_nontemporal_load(&colsrc[j]);
                dstv[u] = isrow ? __builtin_nontemporal_load(&rowdst[j])
                                : __builtin_nontemporal_load(&coldst[j]);
                attv[u] = isrow ? __builtin_nontemporal_load(&ratt[j])
                                : __builtin_nontemporal_load(&catt[j]);
                sfl[u]  = (isrow ? 0 : NN) + s;
                w[u]    = sfl[u] >> 11;           // bucket of 2048 flat-nodes
                rank[u] = atomicAdd(&hcnt[w[u]], 1);
            } else {
                w[u] = -1;
            }
        }
        __syncthreads();
        hbase[tid] = atomicAdd(&wcur[tid], hcnt[tid]);
        __syncthreads();
#pragma unroll
        for (int u = 0; u < 4; ++u) {
            if (w[u] >= 0) {
                int pos = hbase[w[u]] + rank[u];
                psd[pos]  = ((long long)sfl[u] << 32) | (unsigned int)dstv[u];
                patt[pos] = attv[u];
            }
        }
        __syncthreads();   // before hcnt reuse
    }
}

// ---- partB_lds: per-bucket LDS counting sort; writes ptr + sorted edges -------
__global__ __launch_bounds__(512) void partB_lds(
    const int* __restrict__ bbase,
    const long long* __restrict__ psd, const float* __restrict__ patt,
    int* __restrict__ ptr, int2* __restrict__ edges)
{
    __shared__ int lcnt[BKN];          // counts -> (after scan) cursor
    __shared__ long long lrec[CAP];    // sorted records
    __shared__ int sm[512];
    const int tid  = threadIdx.x;
    const int b    = blockIdx.x;
    const int nb0  = b * BKN;
    const int base = bbase[b];
    const int end  = bbase[b + 1];
    const int cnt  = end - base;

    for (int i = tid; i < BKN; i += 512) lcnt[i] = 0;
    __syncthreads();

    // pass1: per-node counts
    for (int i = tid; i < cnt; i += 512) {
        int s = (int)(psd[base + i] >> 32);
        atomicAdd(&lcnt[s - nb0], 1);
    }
    __syncthreads();

    // pass2: block-exclusive scan of 2048 counts (4 per thread);
    // write offsets back into lcnt and global ptr
    int loc[4], tsum = 0;
#pragma unroll
    for (int j = 0; j < 4; ++j) { loc[j] = lcnt[tid * 4 + j]; tsum += loc[j]; }
    sm[tid] = tsum;
    __syncthreads();
    for (int off = 1; off < 512; off <<= 1) {
        int v = (tid >= off) ? sm[tid - off] : 0;
        __syncthreads();
        sm[tid] += v;
        __syncthreads();
    }
    int run = sm[tid] - tsum;
#pragma unroll
    for (int j = 0; j < 4; ++j) {
        lcnt[tid * 4 + j] = run;
        ptr[nb0 + tid * 4 + j] = base + run;
        run += loc[j];
    }
    __syncthreads();

    // pass3: scatter records into LDS (spill path for impossible overflow)
    for (int i = tid; i < cnt; i += 512) {
        long long q = psd[base + i];
        float    a = patt[base + i];
        int s = (int)(q >> 32);
        int d = (int)(q & 0xffffffffLL);
        int off = atomicAdd(&lcnt[s - nb0], 1);
        long long rec = ((long long)__float_as_int(a) << 32) | (unsigned int)d;
        if (off < CAP) lrec[off] = rec;
        else edges[base + off] = make_int2(d, __float_as_int(a));
    }
    __syncthreads();

    // pass4: sequential coalesced write of sorted records
    const int lim = (cnt < CAP) ? cnt : CAP;
    for (int i = tid; i < lim; i += 512) {
        long long rec = lrec[i];
        edges[base + i] = make_int2((int)(rec & 0xffffffffLL), (int)(rec >> 32));
    }
}

// ---- pure gather, 4 concurrent streams per wave (R9-proven version) -----------
__global__ __launch_bounds__(256) void gather_kernel(
    const unsigned short* __restrict__ xnb,
    const int* __restrict__ ptr, const int2* __restrict__ edges,
    unsigned short* __restrict__ rxb, unsigned short* __restrict__ cxb,
    float2* __restrict__ attsum)
{
    const int lane = threadIdx.x & 63;
    const int wid  = (blockIdx.x * 256 + threadIdx.x) >> 6;
    const int nw   = (gridDim.x * 256) >> 6;
    const int HALF = NN / 2;

    for (int n = wid; n < HALF; n += nw) {
        const int m = n + HALF;
        const int i0 = ptr[n],      e0 = ptr[n + 1];
        const int i1 = ptr[NN + n], e1 = ptr[NN + n + 1];
        const int i2 = ptr[m],      e2 = ptr[m + 1];
        const int i3 = ptr[NN + m], e3 = ptr[NN + m + 1];
        const int len0 = e0 - i0, len1 = e1 - i1, len2 = e2 - i2, len3 = e3 - i3;
        int maxlen = max(max(len0, len1), max(len2, len3));

        float rx0 = 0.f, cx0 = 0.f, rx1 = 0.f, cx1 = 0.f;
        float ras0 = 0.f, cas0 = 0.f, ras1 = 0.f, cas1 = 0.f;

#pragma unroll 2
        for (int k = 0; k < maxlen; ++k) {
            int j0 = min(i0 + ((k < len0) ? k : 0), 2 * EE - 1);
            int j1 = min(i1 + ((k < len1) ? k : 0), 2 * EE - 1);
            int j2 = min(i2 + ((k < len2) ? k : 0), 2 * EE - 1);
            int j3 = min(i3 + ((k < len3) ? k : 0), 2 * EE - 1);
            int2 p0 = edges[j0];
            int2 p1 = edges[j1];
            int2 p2 = edges[j2];
            int2 p3 = edges[j3];
            float v0 = bf2f(xnb[(size_t)p0.x * 64 + lane]);
            float v1 = bf2f(xnb[(size_t)p1.x * 64 + lane]);
            float v2 = bf2f(xnb[(size_t)p2.x * 64 + lane]);
            float v3 = bf2f(xnb[(size_t)p3.x * 64 + lane]);
            float a0 = (k < len0) ? __int_as_float(p0.y) : 0.f;
            float a1 = (k < len1) ? __int_as_float(p1.y) : 0.f;
            float a2 = (k < len2) ? __int_as_float(p2.y) : 0.f;
            float a3 = (k < len3) ? __int_as_float(p3.y) : 0.f;
            rx0 = fmaf(v0, a0, rx0); ras0 += a0;
            cx0 = fmaf(v1, a1, cx0); cas0 += a1;
            rx1 = fmaf(v2, a2, rx1); ras1 += a2;
            cx1 = fmaf(v3, a3, cx1); cas1 += a3;
        }

        rxb[(size_t)n * 64 + lane] = f2bf(rx0);
        cxb[(size_t)n * 64 + lane] = f2bf(cx0);
        rxb[(size_t)m * 64 + lane] = f2bf(rx1);
        cxb[(size_t)m * 64 + lane] = f2bf(cx1);
        if (lane == 0) {
            attsum[n] = make_float2(ras0, cas0);
            attsum[m] = make_float2(ras1, cas1);
        }
    }
}

// ---- MFMA epilogue: out = bf16(xnb + rx@Wr + cx@Wc + ras·br + cas·bc) ---------
__global__ __launch_bounds__(256) void gemv_mfma(
    const unsigned short* __restrict__ rxb, const unsigned short* __restrict__ cxb,
    const unsigned short* __restrict__ xnb, const float2* __restrict__ attsum,
    const unsigned short* __restrict__ wb16,
    const float* __restrict__ br, const float* __restrict__ bc,
    unsigned short* __restrict__ out, float* __restrict__ stats)
{
    const int lane = threadIdx.x & 63;
    const int wloc = threadIdx.x >> 6;
    const int wid  = (blockIdx.x * 256 + threadIdx.x) >> 6;
    const int nw   = (gridDim.x * 256) >> 6;
    const int lo   = lane & 15;
    const int hi   = lane >> 4;

    const bf16x8* wb = (const bf16x8*)wb16;
    bf16x8 bfr[2][2][4];
#pragma unroll
    for (int m = 0; m < 2; ++m)
#pragma unroll
        for (int kb = 0; kb < 2; ++kb)
#pragma unroll
            for (int t = 0; t < 4; ++t)
                bfr[m][kb][t] = wb[((m * 2 + kb) * 4 + t) * 64 + lane];

    float brv4[4], bcv4[4];
#pragma unroll
    for (int t = 0; t < 4; ++t) {
        brv4[t] = br[t * 16 + lo];
        bcv4[t] = bc[t * 16 + lo];
    }

    float ss[4] = {0.f, 0.f, 0.f, 0.f}, ss2[4] = {0.f, 0.f, 0.f, 0.f};
    const bf16x8* ra = (const bf16x8*)rxb;
    const bf16x8* ca = (const bf16x8*)cxb;

    for (int tile = wid; tile < NN / 16; tile += nw) {
        const int n0 = tile * 16;
        const int arow = n0 + lo;
        bf16x8 a0 = ra[arow * 8 + hi];
        bf16x8 a1 = ra[arow * 8 + 4 + hi];
        bf16x8 c0 = ca[arow * 8 + hi];
        bf16x8 c1 = ca[arow * 8 + 4 + hi];
        float2 an[4];
#pragma unroll
        for (int r = 0; r < 4; ++r) an[r] = attsum[n0 + hi * 4 + r];

#pragma unroll
        for (int t = 0; t < 4; ++t) {
            f32x4 acc = {0.f, 0.f, 0.f, 0.f};
            acc = __builtin_amdgcn_mfma_f32_16x16x32_bf16(a0, bfr[0][0][t], acc, 0, 0, 0);
            acc = __builtin_amdgcn_mfma_f32_16x16x32_bf16(a1, bfr[0][1][t], acc, 0, 0, 0);
            acc = __builtin_amdgcn_mfma_f32_16x16x32_bf16(c0, bfr[1][0][t], acc, 0, 0, 0);
            acc = __builtin_amdgcn_mfma_f32_16x16x32_bf16(c1, bfr[1][1][t], acc, 0, 0, 0);
            const int col = t * 16 + lo;
#pragma unroll
            for (int r = 0; r < 4; ++r) {
                const int n = n0 + hi * 4 + r;
                float v = acc[r] + bf2f(xnb[(size_t)n * 64 + col])
                        + an[r].x * brv4[t] + an[r].y * bcv4[t];
                out[(size_t)n * 64 + col] = f2bf(v);
                ss[t] += v;
                ss2[t] += v * v;
            }
        }
    }

#pragma unroll
    for (int t = 0; t < 4; ++t) {
        ss[t]  += __shfl_xor(ss[t], 16);  ss[t]  += __shfl_xor(ss[t], 32);
        ss2[t] += __shfl_xor(ss2[t], 16); ss2[t] += __shfl_xor(ss2[t], 32);
    }
    __shared__ float ls[4][64], ls2[4][64];
    if (lo == lane) {
#pragma unroll
        for (int t = 0; t < 4; ++t) {
            ls[wloc][t * 16 + lane]  = ss[t];
            ls2[wloc][t * 16 + lane] = ss2[t];
        }
    }
    __syncthreads();
    if (threadIdx.x < 64) {
        int ch = threadIdx.x;
        atomicAdd(&stats[ch],      ls[0][ch] + ls[1][ch] + ls[2][ch] + ls[3][ch]);
        atomicAdd(&stats[64 + ch], ls2[0][ch] + ls2[1][ch] + ls2[2][ch] + ls2[3][ch]);
    }
}

// ------ fused output: BN-affine from stats + leaky -> GEMV -> softmax ----------
__global__ __launch_bounds__(256) void out_kernel(
    const unsigned short* __restrict__ agg, const float* __restrict__ stats,
    const float* __restrict__ bng, const float* __restrict__ bnb,
    const float* __restrict__ smW, const float* __restrict__ smb,
    float* __restrict__ out)
{
    __shared__ float sW[64 * 16];
    __shared__ float acs[64], acb[64];
    for (int i = threadIdx.x; i < 64 * 16; i += 256) sW[i] = smW[i];
    if (threadIdx.x < 64) {
        int c = threadIdx.x;
        float mean = stats[c] * (1.f / NN);
        float var  = stats[64 + c] * (1.f / NN) - mean * mean;
        float a = bng[c] * rsqrtf(var + EPSV);
        acs[c] = a;
        acb[c] = bnb[c] - mean * a;
    }
    __syncthreads();
    const int j = threadIdx.x & 15;
    const int rloc = threadIdx.x >> 4;
    const float bj = smb[j];
    for (int row = blockIdx.x * 16 + rloc; row < NN; row += gridDim.x * 16) {
        float acc = bj;
#pragma unroll
        for (int k = 0; k < 64; ++k) {
            float v = bf2f(agg[(size_t)row * 64 + k]);
            v = v * acs[k] + acb[k];
            v = (v > 0.f) ? v : 0.01f * v;
            acc = fmaf(v, sW[k * 16 + j], acc);
        }
        float m = acc;
#pragma unroll
        for (int off = 8; off > 0; off >>= 1) m = fmaxf(m, __shfl_xor(m, off));
        float e = expf(acc - m);
        float ssum = e;
#pragma unroll
        for (int off = 8; off > 0; off >>= 1) ssum += __shfl_xor(ssum, off);
        out[(size_t)row * 16 + j] = e / ssum;
    }
}

// ------------------------------------------------------------------------------
extern "C" void kernel_launch(void* const* d_in, const int* in_sizes, int n_in,
                              void* d_out, int out_size, void* d_ws, size_t ws_size,
                              hipStream_t stream)
{
    const float* x        = (const float*)d_in[0];
    const float* row_att  = (const float*)d_in[1];
    const float* col_att  = (const float*)d_in[2];
    const float* prelin_W = (const float*)d_in[3];
    const float* prelin_b = (const float*)d_in[4];
    const float* bn0_g    = (const float*)d_in[5];
    const float* bn0_b    = (const float*)d_in[6];
    const float* ln_g     = (const float*)d_in[7];
    const float* ln_b     = (const float*)d_in[8];
    const float* Wrv      = (const float*)d_in[9];
    const float* brv      = (const float*)d_in[10];
    const float* Wcv      = (const float*)d_in[11];
    const float* bcv      = (const float*)d_in[12];
    const float* bn_g     = (const float*)d_in[13];
    const float* bn_b     = (const float*)d_in[14];
    const float* sm_W     = (const float*)d_in[15];
    const float* sm_b     = (const float*)d_in[16];
    const int*   rowsrc   = (const int*)d_in[17];
    const int*   rowdst   = (const int*)d_in[18];
    const int*   colsrc   = (const int*)d_in[19];
    const int*   coldst   = (const int*)d_in[20];
    float* out = (float*)d_out;

    // ---- workspace layout (~175 MB) ----
    const size_t NH = (size_t)NN * 64;
    char* extra = (char*)d_ws;
    unsigned short* A   = (unsigned short*)extra; extra += NH * sizeof(short);
    unsigned short* xnb = (unsigned short*)extra; extra += NH * sizeof(short);
    unsigned short* rxb = (unsigned short*)extra; extra += NH * sizeof(short);
    unsigned short* cxb = (unsigned short*)extra; extra += NH * sizeof(short);
    float2* attsum = (float2*)extra;              extra += (size_t)NN * sizeof(float2);
    float* stats  = (float*)extra;                extra += 3 * 128 * sizeof(float);
    int*   bcnt   = (int*)extra;                  extra += NBKT * sizeof(int);   // zeroed with stats
    unsigned short* wbuf  = (unsigned short*)extra; extra += 16384 * sizeof(short);
    unsigned short* wbufS = (unsigned short*)extra; extra += 14336 * sizeof(short);
    int*   bbase  = (int*)extra;                  extra += (NBKT + 1) * sizeof(int);
    int*   wcur   = (int*)extra;                  extra += NBKT * sizeof(int);
    int*   ptr    = (int*)extra;                  extra += (NB + 1) * sizeof(int);
    int2*  edges  = (int2*)extra;                 extra += 2 * (size_t)EE * sizeof(int2);

    // staging aliases rxb/cxb (dead until first gather; CSR build precedes it)
    long long* psd = (long long*)rxb;   // 2EE*8B = 33.5 MB = rxb exactly
    float*    patt = (float*)cxb;       // 2EE*4B = 16.8 MB (first half of cxb)

    // one memset covers stats (384 f32) + bcnt (256 i32), contiguous
    hipMemsetAsync(stats, 0, (3 * 128 + NBKT) * sizeof(float), stream);

    // ---- CSR build + weight prep ----
    prep_kernel<<<1144, 256, 0, stream>>>(rowsrc, colsrc, bcnt,
                                          Wrv, Wcv, prelin_W, wbuf, wbufS);
    bscan_kernel<<<1, 256, 0, stream>>>(bcnt, bbase, wcur, ptr);
    partA_kernel<<<1024, 256, 0, stream>>>(rowsrc, rowdst, row_att,
                                           colsrc, coldst, col_att,
                                           wcur, psd, patt);
    partB_lds<<<NBKT, 512, 0, stream>>>(bbase, psd, patt, ptr, edges);

    // ---- stem (MFMA, stats fused) ----
    stem_mfma<<<NN / 64, 256, 0, stream>>>(x, wbufS, prelin_b, A, stats);

    // ---- layer 0 ----
    ln_kernel<0><<<4096, 256, 0, stream>>>(A, stats, bn0_g, bn0_b,
                                           ln_g, ln_b, xnb);
    gather_kernel<<<8192, 256, 0, stream>>>(xnb, ptr, edges, rxb, cxb, attsum);
    gemv_mfma<<<2048, 256, 0, stream>>>(rxb, cxb, xnb, attsum, wbuf,
                                        brv, bcv, A, stats + 128);

    // ---- layer 1 ----
    ln_kernel<1><<<4096, 256, 0, stream>>>(A, stats + 128, bn_g, bn_b,
                                           ln_g + 64, ln_b + 64, xnb);
    gather_kernel<<<8192, 256, 0, stream>>>(xnb, ptr, edges, rxb, cxb, attsum);
    gemv_mfma<<<2048, 256, 0, stream>>>(rxb, cxb, xnb, attsum, wbuf + 8192,
                                        brv + 64, bcv + 64, A, stats + 256);

    // ---- output head (BN-affine folded) ----
    out_kernel<<<2048, 256, 0, stream>>>(A, stats + 256, bn_g + 64, bn_b + 64,
                                         sm_W, sm_b, out);
}